// Round 4
// baseline (342.929 us; speedup 1.0000x reference)
//
#include <hip/hip_runtime.h>
#include <math.h>

#define B_ 4
#define T_ 4096
#define E_ 512
#define H_ 8
#define TOPK 24
#define FH 2049
#define FHP 2064
#define F2 2064
#define ZROWS 16512   // B * F2 * 2

typedef __attribute__((ext_vector_type(8))) short bf16x8;
typedef __attribute__((ext_vector_type(4))) float f32x4;

__device__ __forceinline__ unsigned short f2bf(float f) {
    unsigned u = __float_as_uint(f);
    u = (u + 0x7FFFu + ((u >> 16) & 1u)) >> 16;
    return (unsigned short)u;
}
__device__ __forceinline__ float bf2f(unsigned short h) {
    return __uint_as_float(((unsigned)h) << 16);
}

// ------- transpose hidden [B,T,E]->[B,E,T] fp32 + bf16 split (hi) natural -------
__global__ __launch_bounds__(256) void trsp_split(const float* __restrict__ hid,
                                                  float* __restrict__ Htr,
                                                  unsigned short* __restrict__ Ah)
{
    __shared__ float tile[64][68];
    const int b = blockIdx.z;
    const int t0 = blockIdx.x * 64, e0 = blockIdx.y * 64;
    const int r = threadIdx.x >> 4;
    const int c4 = (threadIdx.x & 15) * 4;
#pragma unroll
    for (int s = 0; s < 4; s++) {
        int t = t0 + r + 16 * s;
        float4 v = *(const float4*)&hid[((size_t)b * T_ + t) * E_ + e0 + c4];
        tile[r + 16 * s][c4 + 0] = v.x; tile[r + 16 * s][c4 + 1] = v.y;
        tile[r + 16 * s][c4 + 2] = v.z; tile[r + 16 * s][c4 + 3] = v.w;
        ushort4 hv = make_ushort4(f2bf(v.x), f2bf(v.y), f2bf(v.z), f2bf(v.w));
        *(ushort4*)&Ah[((size_t)b * T_ + t) * E_ + e0 + c4] = hv;
    }
    __syncthreads();
#pragma unroll
    for (int s = 0; s < 4; s++) {
        int e = e0 + r + 16 * s;
        float4 o;
        o.x = tile[c4 + 0][r + 16 * s];
        o.y = tile[c4 + 1][r + 16 * s];
        o.z = tile[c4 + 2][r + 16 * s];
        o.w = tile[c4 + 3][r + 16 * s];
        *(float4*)&Htr[((size_t)b * E_ + e) * T_ + t0 + c4] = o;
    }
}

// ------- split Wv, Wo to bf16 hi -------
__global__ __launch_bounds__(256) void split_w2(const float* __restrict__ wv,
                                                const float* __restrict__ wo,
                                                unsigned short* __restrict__ Wvh,
                                                unsigned short* __restrict__ Woh)
{
    const float* src = blockIdx.y ? wo : wv;
    unsigned short* dst = blockIdx.y ? Woh : Wvh;
    int i = (blockIdx.x * 256 + threadIdx.x) * 4;
    float4 v = *(const float4*)&src[i];
    *(ushort4*)&dst[i] = make_ushort4(f2bf(v.x), f2bf(v.y), f2bf(v.z), f2bf(v.w));
}

// ------- M^T[j,k] = sum_e Wq[e,k]*Wk[e,j], split to bf16 hi/lo -------
__global__ __launch_bounds__(256) void wprep_m(const float* __restrict__ Wq,
                                               const float* __restrict__ Wk,
                                               unsigned short* __restrict__ Mth,
                                               unsigned short* __restrict__ Mtl)
{
    __shared__ float As[8][132];
    __shared__ float Bs[8][132];
    const int j0 = blockIdx.x * 128, k0 = blockIdx.y * 128;
    const int tid = threadIdx.x;
    const int tm = tid & 15, tn = tid >> 4;
    const int le = tid >> 5, lc = (tid & 31) * 4;
    float acc[8][8];
#pragma unroll
    for (int i = 0; i < 8; i++)
#pragma unroll
        for (int j = 0; j < 8; j++) acc[i][j] = 0.f;
    for (int eb = 0; eb < 512; eb += 8) {
        __syncthreads();
        *(float4*)&As[le][lc] = *(const float4*)&Wq[((size_t)(eb + le)) * 512 + k0 + lc];
        *(float4*)&Bs[le][lc] = *(const float4*)&Wk[((size_t)(eb + le)) * 512 + j0 + lc];
        __syncthreads();
#pragma unroll
        for (int e = 0; e < 8; e++) {
            float a[8], bb[8];
            *(float4*)&a[0] = *(float4*)&As[e][4 * tn];
            *(float4*)&a[4] = *(float4*)&As[e][64 + 4 * tn];
            *(float4*)&bb[0] = *(float4*)&Bs[e][4 * tm];
            *(float4*)&bb[4] = *(float4*)&Bs[e][64 + 4 * tm];
#pragma unroll
            for (int i = 0; i < 8; i++)
#pragma unroll
                for (int j = 0; j < 8; j++)
                    acc[i][j] += a[i] * bb[j];
        }
    }
#pragma unroll
    for (int jj = 0; jj < 8; jj++) {
        int j = j0 + ((jj < 4) ? (4 * tm + jj) : (64 + 4 * tm + jj - 4));
        ushort4 h0, l0, h1, l1;
        float v0[4] = {acc[0][jj], acc[1][jj], acc[2][jj], acc[3][jj]};
        float v1[4] = {acc[4][jj], acc[5][jj], acc[6][jj], acc[7][jj]};
        unsigned short hh[4], ll[4];
#pragma unroll
        for (int r = 0; r < 4; r++) { hh[r] = f2bf(v0[r]); ll[r] = f2bf(v0[r] - bf2f(hh[r])); }
        h0 = make_ushort4(hh[0], hh[1], hh[2], hh[3]); l0 = make_ushort4(ll[0], ll[1], ll[2], ll[3]);
#pragma unroll
        for (int r = 0; r < 4; r++) { hh[r] = f2bf(v1[r]); ll[r] = f2bf(v1[r] - bf2f(hh[r])); }
        h1 = make_ushort4(hh[0], hh[1], hh[2], hh[3]); l1 = make_ushort4(ll[0], ll[1], ll[2], ll[3]);
        *(ushort4*)&Mth[(size_t)j * 512 + k0 + 4 * tn] = h0;
        *(ushort4*)&Mtl[(size_t)j * 512 + k0 + 4 * tn] = l0;
        *(ushort4*)&Mth[(size_t)j * 512 + k0 + 64 + 4 * tn] = h1;
        *(ushort4*)&Mtl[(size_t)j * 512 + k0 + 64 + 4 * tn] = l1;
    }
}

// ---------------- MFMA GEMM: C[n,m] = sum_k A[n,k]*B[m,k] (+ bias[m]) ----------------
// PASSES: 1 or 3 (split).  AMODE: 0 = row-major [N,512], 1 = e-blocked Z layout.
// OMODE: 0 = fp32 [N,512], 2 = bf16 [N,512].  HASBIAS: 0/1.  M is always 512.
template<int PASSES, int AMODE, int OMODE, int HASBIAS>
__global__ __launch_bounds__(256) void mfma_gemm(const unsigned short* __restrict__ Ah,
                                                 const unsigned short* __restrict__ Al,
                                                 const unsigned short* __restrict__ Bh,
                                                 const unsigned short* __restrict__ Bl,
                                                 const float* __restrict__ bias,
                                                 void* __restrict__ Cp)
{
    constexpr int NT = (PASSES == 3) ? 4 : 2;
    constexpr int TSZ = 128 * 40;
    __shared__ short smem[NT * TSZ];
    const int tid = threadIdx.x;
    const int m0 = blockIdx.x * 128;
    const int n0 = blockIdx.y * 128;
    const int wid = tid >> 6, lane = tid & 63;
    const int wn = wid >> 1, wm = wid & 1;
    const int lr = lane & 15, lg = lane >> 4;
    const int kb = lg * 8;

    short* At  = smem;
    short* Alt = smem + ((PASSES == 3) ? TSZ : 0);
    short* Bt  = smem + ((PASSES == 3) ? 2 : 1) * TSZ;
    short* Blt = smem + ((PASSES == 3) ? 3 : 1) * TSZ;

    f32x4 acc[4][4];
#pragma unroll
    for (int i = 0; i < 4; i++)
#pragma unroll
        for (int j = 0; j < 4; j++) acc[i][j] = (f32x4)0.f;

    const int r0 = tid >> 2, kp0 = (tid & 3) << 3;
    const int r1 = (tid + 256) >> 2, kp1 = ((tid + 256) & 3) << 3;

    for (int k0 = 0; k0 < 512; k0 += 32) {
        __syncthreads();
        size_t a0, a1;
        if (AMODE == 0) {
            a0 = (size_t)(n0 + r0) * 512 + k0 + kp0;
            a1 = (size_t)(n0 + r1) * 512 + k0 + kp1;
        } else {
            a0 = ((size_t)((k0 + kp0) >> 3) * ZROWS + n0 + r0) * 8;
            a1 = ((size_t)((k0 + kp1) >> 3) * ZROWS + n0 + r1) * 8;
        }
        *(bf16x8*)&At[r0 * 40 + kp0] = *(const bf16x8*)&Ah[a0];
        *(bf16x8*)&At[r1 * 40 + kp1] = *(const bf16x8*)&Ah[a1];
        *(bf16x8*)&Bt[r0 * 40 + kp0] = *(const bf16x8*)&Bh[(size_t)(m0 + r0) * 512 + k0 + kp0];
        *(bf16x8*)&Bt[r1 * 40 + kp1] = *(const bf16x8*)&Bh[(size_t)(m0 + r1) * 512 + k0 + kp1];
        if (PASSES == 3) {
            *(bf16x8*)&Alt[r0 * 40 + kp0] = *(const bf16x8*)&Al[a0];
            *(bf16x8*)&Alt[r1 * 40 + kp1] = *(const bf16x8*)&Al[a1];
            *(bf16x8*)&Blt[r0 * 40 + kp0] = *(const bf16x8*)&Bl[(size_t)(m0 + r0) * 512 + k0 + kp0];
            *(bf16x8*)&Blt[r1 * 40 + kp1] = *(const bf16x8*)&Bl[(size_t)(m0 + r1) * 512 + k0 + kp1];
        }
        __syncthreads();
        bf16x8 a[4], b[4];
#pragma unroll
        for (int f = 0; f < 4; f++) {
            a[f] = *(bf16x8*)&At[(wn * 64 + f * 16 + lr) * 40 + kb];
            b[f] = *(bf16x8*)&Bt[(wm * 64 + f * 16 + lr) * 40 + kb];
        }
        if (PASSES == 3) {
            bf16x8 a2[4], b2[4];
#pragma unroll
            for (int f = 0; f < 4; f++) {
                a2[f] = *(bf16x8*)&Alt[(wn * 64 + f * 16 + lr) * 40 + kb];
                b2[f] = *(bf16x8*)&Blt[(wm * 64 + f * 16 + lr) * 40 + kb];
            }
#pragma unroll
            for (int i = 0; i < 4; i++)
#pragma unroll
                for (int j = 0; j < 4; j++) {
                    acc[i][j] = __builtin_amdgcn_mfma_f32_16x16x32_bf16(a[i], b[j], acc[i][j], 0, 0, 0);
                    acc[i][j] = __builtin_amdgcn_mfma_f32_16x16x32_bf16(a[i], b2[j], acc[i][j], 0, 0, 0);
                    acc[i][j] = __builtin_amdgcn_mfma_f32_16x16x32_bf16(a2[i], b[j], acc[i][j], 0, 0, 0);
                }
        } else {
#pragma unroll
            for (int i = 0; i < 4; i++)
#pragma unroll
                for (int j = 0; j < 4; j++)
                    acc[i][j] = __builtin_amdgcn_mfma_f32_16x16x32_bf16(a[i], b[j], acc[i][j], 0, 0, 0);
        }
    }

    float bs[4];
#pragma unroll
    for (int j = 0; j < 4; j++) bs[j] = HASBIAS ? bias[m0 + wm * 64 + j * 16 + lr] : 0.f;

    if (OMODE == 0) {
        float* C = (float*)Cp;
#pragma unroll
        for (int i = 0; i < 4; i++)
#pragma unroll
            for (int j = 0; j < 4; j++) {
                int m = m0 + wm * 64 + j * 16 + lr;
#pragma unroll
                for (int r = 0; r < 4; r++) {
                    int n = n0 + wn * 64 + i * 16 + lg * 4 + r;
                    C[(size_t)n * 512 + m] = acc[i][j][r] + bs[j];
                }
            }
    } else {
        unsigned short* C = (unsigned short*)Cp;
#pragma unroll
        for (int i = 0; i < 4; i++)
#pragma unroll
            for (int j = 0; j < 4; j++) {
                int m = m0 + wm * 64 + j * 16 + lr;
#pragma unroll
                for (int r = 0; r < 4; r++) {
                    int n = n0 + wn * 64 + i * 16 + lg * 4 + r;
                    C[(size_t)n * 512 + m] = f2bf(acc[i][j][r] + bs[j]);
                }
            }
    }
}

// ================= radix-8 register FFT (N = 4096 = 8^4) =================
template<int SGN>
__device__ __forceinline__ void radix8(float* xr, float* xi)
{
    const float C = 0.70710678118654752440f;
    const float S = (float)SGN;
    float t0r = xr[0] + xr[4], t0i = xi[0] + xi[4];
    float t1r = xr[1] + xr[5], t1i = xi[1] + xi[5];
    float t2r = xr[2] + xr[6], t2i = xi[2] + xi[6];
    float t3r = xr[3] + xr[7], t3i = xi[3] + xi[7];
    float u0r = xr[0] - xr[4], u0i = xi[0] - xi[4];
    float a1r = xr[1] - xr[5], a1i = xi[1] - xi[5];
    float a2r = xr[2] - xr[6], a2i = xi[2] - xi[6];
    float a3r = xr[3] - xr[7], a3i = xi[3] - xi[7];
    float u1r = C * (a1r - S * a1i), u1i = C * (S * a1r + a1i);
    float u2r = -S * a2i,             u2i = S * a2r;
    float u3r = -C * (a3r + S * a3i), u3i = C * (S * a3r - a3i);
    float v0r = t0r + t2r, v0i = t0i + t2i;
    float w0r = t0r - t2r, w0i = t0i - t2i;
    float v1r = t1r + t3r, v1i = t1i + t3i;
    float w1r = -S * (t1i - t3i), w1i = S * (t1r - t3r);
    float p0r = u0r + u2r, p0i = u0i + u2i;
    float q0r = u0r - u2r, q0i = u0i - u2i;
    float p1r = u1r + u3r, p1i = u1i + u3i;
    float q1r = -S * (u1i - u3i), q1i = S * (u1r - u3r);
    xr[0] = v0r + v1r; xi[0] = v0i + v1i;
    xr[4] = v0r - v1r; xi[4] = v0i - v1i;
    xr[2] = w0r + w1r; xi[2] = w0i + w1i;
    xr[6] = w0r - w1r; xi[6] = w0i - w1i;
    xr[1] = p0r + p1r; xi[1] = p0i + p1i;
    xr[5] = p0r - p1r; xi[5] = p0i - p1i;
    xr[3] = q0r + q1r; xi[3] = q0i + q1i;
    xr[7] = q0r - q1r; xi[7] = q0i - q1i;
}

__device__ __forceinline__ void twmul(float& xr, float& xi, float wc, float ws)
{
    float a = xr, b = xi;
    xr = a * wc - b * ws;
    xi = a * ws + b * wc;
}

__device__ __forceinline__ void twiddle7(float* xr, float* xi, int n, float ang)
{
    float s1, c1;
    __sincosf(ang * (float)n, &s1, &c1);
    float wc = c1, ws = s1;
    twmul(xr[1], xi[1], wc, ws);
#pragma unroll
    for (int r = 2; r < 8; r++) {
        float nc = wc * c1 - ws * s1;
        float ns = wc * s1 + ws * c1;
        wc = nc; ws = ns;
        twmul(xr[r], xi[r], wc, ws);
    }
}

#define SW(i) ((i) + ((i) >> 3))

template<int SGN>
__device__ __forceinline__ void fft_core(float* xr, float* xi,
                                         float* lre, float* lim, int tid)
{
    const float TW = (float)SGN * 6.28318530717958647693f;
    __syncthreads();
    radix8<SGN>(xr, xi);
    twiddle7(xr, xi, tid, TW / 4096.f);
#pragma unroll
    for (int r = 0; r < 8; r++) {
        int idx = r * 512 + tid;
        lre[SW(idx)] = xr[r]; lim[SW(idx)] = xi[r];
    }
    __syncthreads();
    const int b2 = (tid >> 6) * 512, n2 = tid & 63;
#pragma unroll
    for (int s = 0; s < 8; s++) {
        int idx = b2 + n2 + s * 64;
        xr[s] = lre[SW(idx)]; xi[s] = lim[SW(idx)];
    }
    __syncthreads();
    radix8<SGN>(xr, xi);
    twiddle7(xr, xi, n2, TW / 512.f);
#pragma unroll
    for (int r = 0; r < 8; r++) {
        int idx = b2 + r * 64 + n2;
        lre[SW(idx)] = xr[r]; lim[SW(idx)] = xi[r];
    }
    __syncthreads();
    const int b3 = (tid >> 3) * 64, n3 = tid & 7;
#pragma unroll
    for (int s = 0; s < 8; s++) {
        int idx = b3 + n3 + s * 8;
        xr[s] = lre[SW(idx)]; xi[s] = lim[SW(idx)];
    }
    __syncthreads();
    radix8<SGN>(xr, xi);
    twiddle7(xr, xi, n3, TW / 64.f);
#pragma unroll
    for (int r = 0; r < 8; r++) {
        int idx = b3 + r * 8 + n3;
        lre[SW(idx)] = xr[r]; lim[SW(idx)] = xi[r];
    }
    __syncthreads();
#pragma unroll
    for (int s = 0; s < 8; s++) {
        int idx = tid * 8 + s;
        xr[s] = lre[SW(idx)]; xi[s] = lim[SW(idx)];
    }
    __syncthreads();
    radix8<SGN>(xr, xi);
    const int fr = ((tid & 7) << 6) | (((tid >> 3) & 7) << 3) | (tid >> 6);
#pragma unroll
    for (int r = 0; r < 8; r++) {
        int f = r * 512 + fr;
        lre[SW(f)] = xr[r]; lim[SW(f)] = xi[r];
    }
    __syncthreads();
}

// ------- forward FFT of hidden: 8 channels/block, write split Z (e-blocked) -------
__global__ __launch_bounds__(512) void fft_fwd_z(const float* __restrict__ Htr,
                                                 unsigned short* __restrict__ Zh,
                                                 unsigned short* __restrict__ Zl)
{
    __shared__ float lre[4608];
    __shared__ float lim[4608];
    const int bid = blockIdx.x;          // 0..255
    const int tid = threadIdx.x;
    const int b = bid >> 6, g = bid & 63;
    const int e0 = g * 8;
    unsigned uh[4][2][4], ul[4][2][4];
#pragma unroll
    for (int p = 0; p < 4; p++) {
        const float* he = Htr + ((size_t)(b * 512 + e0 + 2 * p)) * 4096;
        const float* ho = Htr + ((size_t)(b * 512 + e0 + 2 * p + 1)) * 4096;
        float xr[8], xi[8];
#pragma unroll
        for (int s = 0; s < 8; s++) {
            xr[s] = he[tid + 512 * s];
            xi[s] = ho[tid + 512 * s];
        }
        fft_core<-1>(xr, xi, lre, lim, tid);
#pragma unroll
        for (int s = 0; s < 4; s++) {
            int f = tid + 512 * s;
            int nf = (4096 - f) & 4095;
            float Ax = lre[SW(f)],  Ay = lim[SW(f)];
            float Bx = lre[SW(nf)], By = lim[SW(nf)];
            float qx = 0.5f * (Ax + Bx), qy = 0.5f * (Ay - By);   // chan even (re,im)
            float kx = 0.5f * (Ay + By), ky = -0.5f * (Ax - Bx);  // chan odd
            unsigned short h0 = f2bf(qx), h1 = f2bf(kx);
            unsigned short l0 = f2bf(qx - bf2f(h0)), l1 = f2bf(kx - bf2f(h1));
            uh[s][0][p] = (unsigned)h0 | ((unsigned)h1 << 16);
            ul[s][0][p] = (unsigned)l0 | ((unsigned)l1 << 16);
            unsigned short h2 = f2bf(qy), h3 = f2bf(ky);
            unsigned short l2 = f2bf(qy - bf2f(h2)), l3 = f2bf(ky - bf2f(h3));
            uh[s][1][p] = (unsigned)h2 | ((unsigned)h3 << 16);
            ul[s][1][p] = (unsigned)l2 | ((unsigned)l3 << 16);
        }
        if (tid == 0) {
            float Ax = lre[SW(2048)], Ay = lim[SW(2048)];
            size_t r2048 = ((size_t)b * F2 + 2048) * 2;
            size_t base0 = ((size_t)g * ZROWS + r2048) * 8 + 2 * p;
            unsigned short h = f2bf(Ax);
            Zh[base0] = h; Zl[base0] = f2bf(Ax - bf2f(h));
            unsigned short h2 = f2bf(Ay);
            Zh[base0 + 1] = h2; Zl[base0 + 1] = f2bf(Ay - bf2f(h2));
            size_t base1 = ((size_t)g * ZROWS + r2048 + 1) * 8 + 2 * p;
            Zh[base1] = 0; Zl[base1] = 0;
            Zh[base1 + 1] = 0; Zl[base1 + 1] = 0;
        }
    }
#pragma unroll
    for (int s = 0; s < 4; s++)
#pragma unroll
        for (int c = 0; c < 2; c++) {
            size_t row = ((size_t)b * F2 + tid + 512 * s) * 2 + c;
            size_t off = ((size_t)g * ZROWS + row) * 8;
            bf16x8 vh, vl;
#pragma unroll
            for (int p = 0; p < 4; p++) {
                vh[2 * p]     = (short)(uh[s][c][p] & 0xffff);
                vh[2 * p + 1] = (short)(uh[s][c][p] >> 16);
                vl[2 * p]     = (short)(ul[s][c][p] & 0xffff);
                vl[2 * p + 1] = (short)(ul[s][c][p] >> 16);
            }
            *(bf16x8*)&Zh[off] = vh;
            *(bf16x8*)&Zl[off] = vl;
        }
}

// ------- S[b,f] = sum_j Y[row(f),j] * conj(z[j]) -------
__global__ __launch_bounds__(256) void dot_s(const float* __restrict__ Y,
                                             const unsigned short* __restrict__ Zh,
                                             const unsigned short* __restrict__ Zl,
                                             float2* __restrict__ S)
{
    const int lane = threadIdx.x & 63, w = threadIdx.x >> 6;
    const int f = blockIdx.x * 256 + w * 64 + lane;
    const int b = blockIdx.y;
    if (f > 2048) return;
    const size_t row = ((size_t)b * F2 + f) * 2;
    float sre = 0.f, sim = 0.f;
    for (int g = 0; g < 64; g++) {
        size_t zoff = ((size_t)g * ZROWS + row) * 8;
        bf16x8 zrh = *(const bf16x8*)&Zh[zoff];
        bf16x8 zrl = *(const bf16x8*)&Zl[zoff];
        bf16x8 zih = *(const bf16x8*)&Zh[zoff + 8];
        bf16x8 zil = *(const bf16x8*)&Zl[zoff + 8];
        const float* yr = &Y[row * 512 + g * 8];
        const float* yi = &Y[(row + 1) * 512 + g * 8];
        float4 yr0 = *(const float4*)yr,       yr1 = *(const float4*)(yr + 4);
        float4 yi0 = *(const float4*)yi,       yi1 = *(const float4*)(yi + 4);
        float yrv[8] = {yr0.x, yr0.y, yr0.z, yr0.w, yr1.x, yr1.y, yr1.z, yr1.w};
        float yiv[8] = {yi0.x, yi0.y, yi0.z, yi0.w, yi1.x, yi1.y, yi1.z, yi1.w};
#pragma unroll
        for (int j = 0; j < 8; j++) {
            float zr = bf2f((unsigned short)zrh[j]) + bf2f((unsigned short)zrl[j]);
            float zi = bf2f((unsigned short)zih[j]) + bf2f((unsigned short)zil[j]);
            sre += yrv[j] * zr + yiv[j] * zi;
            sim += yiv[j] * zr - yrv[j] * zi;
        }
    }
    S[b * FHP + f] = make_float2(sre, sim);
}

// ---------------- inverse FFT -> ac_mean ----------------
__global__ __launch_bounds__(512) void ifft_kernel(const float2* __restrict__ S,
                                                   float* __restrict__ acm)
{
    __shared__ float lre[4608];
    __shared__ float lim[4608];
    const int b = blockIdx.x, tid = threadIdx.x;
    float xr[8], xi[8];
#pragma unroll
    for (int s = 0; s < 8; s++) {
        int idx = tid + 512 * s;
        if (idx <= 2048) {
            float2 v = S[b * FHP + idx];
            xr[s] = v.x; xi[s] = v.y;
        } else {
            float2 v = S[b * FHP + (4096 - idx)];
            xr[s] = v.x; xi[s] = -v.y;
        }
    }
    fft_core<1>(xr, xi, lre, lim, tid);
    const float scale = 1.0f / ((float)T_ * (float)E_);
#pragma unroll
    for (int s = 0; s < 8; s++) {
        int p = tid + 512 * s;
        acm[b * T_ + p] = lre[SW(p)] * scale;
    }
}

// ---------------- top-k (24) + softmax, per batch ----------------
__global__ __launch_bounds__(256) void topk_kernel(const float* __restrict__ acm,
                                                   int* __restrict__ delays,
                                                   float* __restrict__ weights)
{
    __shared__ float vals[4096];
    __shared__ float bv[256];
    __shared__ int   bi[256];
    __shared__ float topv[TOPK];
    const int b = blockIdx.x, tid = threadIdx.x;
#pragma unroll
    for (int s = 0; s < 16; s++) vals[tid + 256 * s] = acm[b * T_ + tid + 256 * s];
    __syncthreads();
    for (int it = 0; it < TOPK; it++) {
        float best = -INFINITY; int bidx = 0;
#pragma unroll
        for (int s = 0; s < 16; s++) {
            int idx = tid * 16 + s;
            float v = vals[idx];
            if (v > best) { best = v; bidx = idx; }
        }
        bv[tid] = best; bi[tid] = bidx;
        __syncthreads();
        for (int off = 128; off > 0; off >>= 1) {
            if (tid < off) {
                if (bv[tid + off] > bv[tid] ||
                    (bv[tid + off] == bv[tid] && bi[tid + off] < bi[tid])) {
                    bv[tid] = bv[tid + off]; bi[tid] = bi[tid + off];
                }
            }
            __syncthreads();
        }
        if (tid == 0) {
            delays[b * TOPK + it] = bi[0];
            topv[it] = bv[0];
            vals[bi[0]] = -INFINITY;
        }
        __syncthreads();
    }
    if (tid == 0) {
        float mx = topv[0];
        float w[TOPK], sum = 0.f;
        for (int i = 0; i < TOPK; i++) { w[i] = expf(topv[i] - mx); sum += w[i]; }
        for (int i = 0; i < TOPK; i++) weights[b * TOPK + i] = w[i] / sum;
    }
}

// ---------------- agg: weighted circular gather of bf16 V ----------------
__global__ __launch_bounds__(256) void agg_kernel(const unsigned short* __restrict__ V,
                                                  const int* __restrict__ delays,
                                                  const float* __restrict__ wts,
                                                  unsigned short* __restrict__ agg)
{
    __shared__ int   dly[B_][TOPK];
    __shared__ float wt[B_][TOPK];
    const int tid = threadIdx.x, b = blockIdx.y;
    if (tid < B_ * TOPK) {
        dly[tid / TOPK][tid % TOPK] = delays[tid];
        wt[tid / TOPK][tid % TOPK]  = wts[tid];
    }
    __syncthreads();
    const int lane = tid & 63, w = tid >> 6;
    const int t = blockIdx.x * 4 + w;
    const int e8 = lane * 8;
    const int h = e8 >> 6;
    const int c = (b * H_ + h) % B_;
    const unsigned short* Vb = V + (size_t)b * T_ * E_;
    float acc[8];
#pragma unroll
    for (int j = 0; j < 8; j++) acc[j] = 0.f;
#pragma unroll
    for (int i = 0; i < TOPK; i++) {
        int tt = (t + dly[c][i]) & (T_ - 1);
        bf16x8 v = *(const bf16x8*)&Vb[(size_t)tt * E_ + e8];
        float wg = wt[c][i];
#pragma unroll
        for (int j = 0; j < 8; j++)
            acc[j] += wg * bf2f((unsigned short)v[j]);
    }
    bf16x8 o;
#pragma unroll
    for (int j = 0; j < 8; j++) o[j] = (short)f2bf(acc[j]);
    *(bf16x8*)&agg[((size_t)b * T_ + t) * E_ + e8] = o;
}

// ---------------- launch ----------------
extern "C" void kernel_launch(void* const* d_in, const int* in_sizes, int n_in,
                              void* d_out, int out_size, void* d_ws, size_t ws_size,
                              hipStream_t stream)
{
    const float* hidden = (const float*)d_in[0];
    const float* Wq = (const float*)d_in[1];
    const float* Wk = (const float*)d_in[3];
    const float* Wv = (const float*)d_in[5]; const float* bv = (const float*)d_in[6];
    const float* Wo = (const float*)d_in[7]; const float* bo = (const float*)d_in[8];

    char* ws = (char*)d_ws;
    const size_t YA_OFF  = 0;                  // 33.8 MB: Htr fp32, later Y fp32
    const size_t AH_OFF  = 33816576;           // 16.8 MB: Ah bf16, later Ag bf16
    const size_t ZH_OFF  = 50593792;           // 16.9 MB
    const size_t ZL_OFF  = 67502080;           // 16.9 MB
    const size_t VB_OFF  = 84410368;           // 16.8 MB
    const size_t MTH_OFF = 101187584;          // 512 KB
    const size_t MTL_OFF = 101711872;          // 512 KB
    const size_t WVH_OFF = 102236160;          // 512 KB
    const size_t WOH_OFF = 102760448;          // 512 KB
    const size_t S_OFF   = 103284736;          // 66 KB
    const size_t ACM_OFF = 103350784;          // 64 KB
    const size_t DEL_OFF = 103416320;          // 384 B
    const size_t WTS_OFF = 103416704;          // 384 B
    if (ws_size < 103417088) return;

    float* Htr = (float*)(ws + YA_OFF);
    float* Y   = (float*)(ws + YA_OFF);
    unsigned short* Ah  = (unsigned short*)(ws + AH_OFF);
    unsigned short* Ag  = (unsigned short*)(ws + AH_OFF);
    unsigned short* Zh  = (unsigned short*)(ws + ZH_OFF);
    unsigned short* Zl  = (unsigned short*)(ws + ZL_OFF);
    unsigned short* Vb  = (unsigned short*)(ws + VB_OFF);
    unsigned short* Mth = (unsigned short*)(ws + MTH_OFF);
    unsigned short* Mtl = (unsigned short*)(ws + MTL_OFF);
    unsigned short* Wvh = (unsigned short*)(ws + WVH_OFF);
    unsigned short* Woh = (unsigned short*)(ws + WOH_OFF);
    float2* S    = (float2*)(ws + S_OFF);
    float*  acm  = (float*)(ws + ACM_OFF);
    int*    delays = (int*)(ws + DEL_OFF);
    float*  wts    = (float*)(ws + WTS_OFF);

    // prep: transpose+split hidden; split Wv/Wo; M = Wq^T Wk (transposed, split)
    dim3 tg(64, 8, 4);
    trsp_split<<<tg, 256, 0, stream>>>(hidden, Htr, Ah);
    dim3 swg(256, 2);
    split_w2<<<swg, 256, 0, stream>>>(Wv, Wo, Wvh, Woh);
    dim3 mg(4, 4);
    wprep_m<<<mg, 256, 0, stream>>>(Wq, Wk, Mth, Mtl);

    // V GEMM (bf16 out) — frees Ah afterwards
    dim3 gv(4, 128);
    mfma_gemm<1, 0, 2, 1><<<gv, 256, 0, stream>>>(Ah, Ah, Wvh, Wvh, bv, Vb);

    // FFT of hidden -> split Z (e-blocked) — frees Htr afterwards
    fft_fwd_z<<<256, 512, 0, stream>>>(Htr, Zh, Zl);

    // Y = Z * M^T (3-pass split), fp32 out into Htr-space
    dim3 gy(4, 129);
    mfma_gemm<3, 1, 0, 0><<<gy, 256, 0, stream>>>(Zh, Zl, Mth, Mtl, bv, Y);

    // S[b,f] = sum_j Y[f,j] * conj(z[f,j])
    dim3 dg(9, 4);
    dot_s<<<dg, 256, 0, stream>>>(Y, Zh, Zl, S);

    // ac_mean, top-k, weighted gather, output projection
    ifft_kernel<<<B_, 512, 0, stream>>>(S, acm);
    topk_kernel<<<B_, 256, 0, stream>>>(acm, delays, wts);
    dim3 ag(T_ / 4, B_);
    agg_kernel<<<ag, 256, 0, stream>>>(Vb, delays, wts, Ag);
    mfma_gemm<1, 0, 0, 1><<<gv, 256, 0, stream>>>(Ag, Ag, Woh, Woh, bo, (float*)d_out);
}

// Round 6
// 310.302 us; speedup vs baseline: 1.1051x; 1.1051x over previous
//
#include <hip/hip_runtime.h>
#include <math.h>

#define B_ 4
#define T_ 4096
#define E_ 512
#define H_ 8
#define TOPK 24
#define FH 2049
#define FHP 2064
#define F2 2064
#define ZROWS 16512   // B * 2 * F2  (plane-major: row = (b*2+plane)*F2 + f)

typedef __attribute__((ext_vector_type(8))) short bf16x8;
typedef __attribute__((ext_vector_type(4))) short bf16x4;
typedef __attribute__((ext_vector_type(4))) float f32x4;

__device__ __forceinline__ unsigned short f2bf(float f) {
    unsigned u = __float_as_uint(f);
    u = (u + 0x7FFFu + ((u >> 16) & 1u)) >> 16;
    return (unsigned short)u;
}
__device__ __forceinline__ float bf2f(unsigned short h) {
    return __uint_as_float(((unsigned)h) << 16);
}

// ------- transpose hidden [B,T,E]->[B,E,T] fp32 + bf16 (hi) natural -------
__global__ __launch_bounds__(256) void trsp_split(const float* __restrict__ hid,
                                                  float* __restrict__ Htr,
                                                  unsigned short* __restrict__ Ah)
{
    __shared__ float tile[64][68];
    const int b = blockIdx.z;
    const int t0 = blockIdx.x * 64, e0 = blockIdx.y * 64;
    const int r = threadIdx.x >> 4;
    const int c4 = (threadIdx.x & 15) * 4;
#pragma unroll
    for (int s = 0; s < 4; s++) {
        int t = t0 + r + 16 * s;
        float4 v = *(const float4*)&hid[((size_t)b * T_ + t) * E_ + e0 + c4];
        tile[r + 16 * s][c4 + 0] = v.x; tile[r + 16 * s][c4 + 1] = v.y;
        tile[r + 16 * s][c4 + 2] = v.z; tile[r + 16 * s][c4 + 3] = v.w;
        ushort4 hv = make_ushort4(f2bf(v.x), f2bf(v.y), f2bf(v.z), f2bf(v.w));
        *(ushort4*)&Ah[((size_t)b * T_ + t) * E_ + e0 + c4] = hv;
    }
    __syncthreads();
#pragma unroll
    for (int s = 0; s < 4; s++) {
        int e = e0 + r + 16 * s;
        float4 o;
        o.x = tile[c4 + 0][r + 16 * s];
        o.y = tile[c4 + 1][r + 16 * s];
        o.z = tile[c4 + 2][r + 16 * s];
        o.w = tile[c4 + 3][r + 16 * s];
        *(float4*)&Htr[((size_t)b * E_ + e) * T_ + t0 + c4] = o;
    }
}

// ------- split Wv, Wo to bf16 hi -------
__global__ __launch_bounds__(256) void split_w2(const float* __restrict__ wv,
                                                const float* __restrict__ wo,
                                                unsigned short* __restrict__ Wvh,
                                                unsigned short* __restrict__ Woh)
{
    const float* src = blockIdx.y ? wo : wv;
    unsigned short* dst = blockIdx.y ? Woh : Wvh;
    int i = (blockIdx.x * 256 + threadIdx.x) * 4;
    float4 v = *(const float4*)&src[i];
    *(ushort4*)&dst[i] = make_ushort4(f2bf(v.x), f2bf(v.y), f2bf(v.z), f2bf(v.w));
}

// ------- M^T partials: Mp[z][j][k] = sum_{e in chunk z} Wq[e,k]*Wk[e,j] -------
__global__ __launch_bounds__(256) void wprep_partial(const float* __restrict__ Wq,
                                                     const float* __restrict__ Wk,
                                                     float* __restrict__ Mp)
{
    __shared__ float As[8][132];
    __shared__ float Bs[8][132];
    const int j0 = blockIdx.x * 128, k0 = blockIdx.y * 128;
    const int e0 = blockIdx.z * 32;
    const int tid = threadIdx.x;
    const int tm = tid & 15, tn = tid >> 4;
    const int le = tid >> 5, lc = (tid & 31) * 4;
    float acc[8][8];
#pragma unroll
    for (int i = 0; i < 8; i++)
#pragma unroll
        for (int j = 0; j < 8; j++) acc[i][j] = 0.f;
    for (int eb = e0; eb < e0 + 32; eb += 8) {
        __syncthreads();
        *(float4*)&As[le][lc] = *(const float4*)&Wq[((size_t)(eb + le)) * 512 + k0 + lc];
        *(float4*)&Bs[le][lc] = *(const float4*)&Wk[((size_t)(eb + le)) * 512 + j0 + lc];
        __syncthreads();
#pragma unroll
        for (int e = 0; e < 8; e++) {
            float a[8], bb[8];
            *(float4*)&a[0] = *(float4*)&As[e][4 * tn];
            *(float4*)&a[4] = *(float4*)&As[e][64 + 4 * tn];
            *(float4*)&bb[0] = *(float4*)&Bs[e][4 * tm];
            *(float4*)&bb[4] = *(float4*)&Bs[e][64 + 4 * tm];
#pragma unroll
            for (int i = 0; i < 8; i++)
#pragma unroll
                for (int j = 0; j < 8; j++)
                    acc[i][j] += a[i] * bb[j];
        }
    }
    float* out = Mp + (size_t)blockIdx.z * 512 * 512;
#pragma unroll
    for (int jj = 0; jj < 8; jj++) {
        int j = j0 + ((jj < 4) ? (4 * tm + jj) : (64 + 4 * tm + jj - 4));
        float4 o0 = make_float4(acc[0][jj], acc[1][jj], acc[2][jj], acc[3][jj]);
        float4 o1 = make_float4(acc[4][jj], acc[5][jj], acc[6][jj], acc[7][jj]);
        *(float4*)&out[(size_t)j * 512 + k0 + 4 * tn] = o0;
        *(float4*)&out[(size_t)j * 512 + k0 + 64 + 4 * tn] = o1;
    }
}

// ------- reduce 16 partials, split to bf16 hi/lo (262144 elements total) -------
__global__ __launch_bounds__(256) void reduce_split_m(const float* __restrict__ Mp,
                                                      unsigned short* __restrict__ Mth,
                                                      unsigned short* __restrict__ Mtl)
{
    int i = (blockIdx.x * 256 + threadIdx.x) * 4;
    if (i >= 512 * 512) return;          // geometry guard
    float4 s = make_float4(0.f, 0.f, 0.f, 0.f);
#pragma unroll
    for (int z = 0; z < 16; z++) {
        float4 v = *(const float4*)&Mp[(size_t)z * 262144 + i];
        s.x += v.x; s.y += v.y; s.z += v.z; s.w += v.w;
    }
    float f[4] = {s.x, s.y, s.z, s.w};
    unsigned short hh[4], ll[4];
#pragma unroll
    for (int r = 0; r < 4; r++) {
        hh[r] = f2bf(f[r]);
        ll[r] = f2bf(f[r] - bf2f(hh[r]));
    }
    *(ushort4*)&Mth[i] = make_ushort4(hh[0], hh[1], hh[2], hh[3]);
    *(ushort4*)&Mtl[i] = make_ushort4(ll[0], ll[1], ll[2], ll[3]);
}

// ---------------- MFMA GEMM: C[n,m] = sum_k A[n,k]*B[m,k] (+ bias[m]) ----------------
// PASSES: 1 or 3.  AMODE: 0 = row-major [N,512], 1 = Z layout [kb][row][4].
// OMODE: 0 = fp32 [N,512], 2 = bf16 [N,512].  HASBIAS: 0/1.
template<int PASSES, int AMODE, int OMODE, int HASBIAS>
__global__ __launch_bounds__(256) void mfma_gemm(const unsigned short* __restrict__ Ah,
                                                 const unsigned short* __restrict__ Al,
                                                 const unsigned short* __restrict__ Bh,
                                                 const unsigned short* __restrict__ Bl,
                                                 const float* __restrict__ bias,
                                                 void* __restrict__ Cp)
{
    constexpr int NT = (PASSES == 3) ? 4 : 2;
    constexpr int TSZ = 128 * 40;
    __shared__ short smem[NT * TSZ];
    const int tid = threadIdx.x;
    const int m0 = blockIdx.x * 128;
    const int n0 = blockIdx.y * 128;
    const int wid = tid >> 6, lane = tid & 63;
    const int wn = wid >> 1, wm = wid & 1;
    const int lr = lane & 15, lg = lane >> 4;
    const int kb = lg * 8;

    short* At  = smem;
    short* Alt = smem + ((PASSES == 3) ? TSZ : 0);
    short* Bt  = smem + ((PASSES == 3) ? 2 : 1) * TSZ;
    short* Blt = smem + ((PASSES == 3) ? 3 : 1) * TSZ;

    f32x4 acc[4][4];
#pragma unroll
    for (int i = 0; i < 4; i++)
#pragma unroll
        for (int j = 0; j < 4; j++) acc[i][j] = (f32x4)0.f;

    const int r0 = tid >> 2, kp0 = (tid & 3) << 3;
    const int r1 = (tid + 256) >> 2, kp1 = ((tid + 256) & 3) << 3;

    for (int k0 = 0; k0 < 512; k0 += 32) {
        __syncthreads();
        if (AMODE == 0) {
            size_t a0 = (size_t)(n0 + r0) * 512 + k0 + kp0;
            size_t a1 = (size_t)(n0 + r1) * 512 + k0 + kp1;
            *(bf16x8*)&At[r0 * 40 + kp0] = *(const bf16x8*)&Ah[a0];
            *(bf16x8*)&At[r1 * 40 + kp1] = *(const bf16x8*)&Ah[a1];
            if (PASSES == 3) {
                *(bf16x8*)&Alt[r0 * 40 + kp0] = *(const bf16x8*)&Al[a0];
                *(bf16x8*)&Alt[r1 * 40 + kp1] = *(const bf16x8*)&Al[a1];
            }
        } else {
            size_t a0 = ((size_t)((k0 + kp0) >> 2) * ZROWS + n0 + r0) * 4;
            size_t a1 = ((size_t)((k0 + kp1) >> 2) * ZROWS + n0 + r1) * 4;
            const size_t st = (size_t)ZROWS * 4;
            *(bf16x4*)&At[r0 * 40 + kp0]     = *(const bf16x4*)&Ah[a0];
            *(bf16x4*)&At[r0 * 40 + kp0 + 4] = *(const bf16x4*)&Ah[a0 + st];
            *(bf16x4*)&At[r1 * 40 + kp1]     = *(const bf16x4*)&Ah[a1];
            *(bf16x4*)&At[r1 * 40 + kp1 + 4] = *(const bf16x4*)&Ah[a1 + st];
            if (PASSES == 3) {
                *(bf16x4*)&Alt[r0 * 40 + kp0]     = *(const bf16x4*)&Al[a0];
                *(bf16x4*)&Alt[r0 * 40 + kp0 + 4] = *(const bf16x4*)&Al[a0 + st];
                *(bf16x4*)&Alt[r1 * 40 + kp1]     = *(const bf16x4*)&Al[a1];
                *(bf16x4*)&Alt[r1 * 40 + kp1 + 4] = *(const bf16x4*)&Al[a1 + st];
            }
        }
        *(bf16x8*)&Bt[r0 * 40 + kp0] = *(const bf16x8*)&Bh[(size_t)(m0 + r0) * 512 + k0 + kp0];
        *(bf16x8*)&Bt[r1 * 40 + kp1] = *(const bf16x8*)&Bh[(size_t)(m0 + r1) * 512 + k0 + kp1];
        if (PASSES == 3) {
            *(bf16x8*)&Blt[r0 * 40 + kp0] = *(const bf16x8*)&Bl[(size_t)(m0 + r0) * 512 + k0 + kp0];
            *(bf16x8*)&Blt[r1 * 40 + kp1] = *(const bf16x8*)&Bl[(size_t)(m0 + r1) * 512 + k0 + kp1];
        }
        __syncthreads();
        bf16x8 a[4], b[4];
#pragma unroll
        for (int f = 0; f < 4; f++) {
            a[f] = *(bf16x8*)&At[(wn * 64 + f * 16 + lr) * 40 + kb];
            b[f] = *(bf16x8*)&Bt[(wm * 64 + f * 16 + lr) * 40 + kb];
        }
        if (PASSES == 3) {
            bf16x8 a2[4], b2[4];
#pragma unroll
            for (int f = 0; f < 4; f++) {
                a2[f] = *(bf16x8*)&Alt[(wn * 64 + f * 16 + lr) * 40 + kb];
                b2[f] = *(bf16x8*)&Blt[(wm * 64 + f * 16 + lr) * 40 + kb];
            }
#pragma unroll
            for (int i = 0; i < 4; i++)
#pragma unroll
                for (int j = 0; j < 4; j++) {
                    acc[i][j] = __builtin_amdgcn_mfma_f32_16x16x32_bf16(a[i], b[j], acc[i][j], 0, 0, 0);
                    acc[i][j] = __builtin_amdgcn_mfma_f32_16x16x32_bf16(a[i], b2[j], acc[i][j], 0, 0, 0);
                    acc[i][j] = __builtin_amdgcn_mfma_f32_16x16x32_bf16(a2[i], b[j], acc[i][j], 0, 0, 0);
                }
        } else {
#pragma unroll
            for (int i = 0; i < 4; i++)
#pragma unroll
                for (int j = 0; j < 4; j++)
                    acc[i][j] = __builtin_amdgcn_mfma_f32_16x16x32_bf16(a[i], b[j], acc[i][j], 0, 0, 0);
        }
    }

    float bs[4];
#pragma unroll
    for (int j = 0; j < 4; j++) bs[j] = HASBIAS ? bias[m0 + wm * 64 + j * 16 + lr] : 0.f;

    if (OMODE == 0) {
        float* C = (float*)Cp;
#pragma unroll
        for (int i = 0; i < 4; i++)
#pragma unroll
            for (int j = 0; j < 4; j++) {
                int m = m0 + wm * 64 + j * 16 + lr;
#pragma unroll
                for (int r = 0; r < 4; r++) {
                    int n = n0 + wn * 64 + i * 16 + lg * 4 + r;
                    C[(size_t)n * 512 + m] = acc[i][j][r] + bs[j];
                }
            }
    } else {
        unsigned short* C = (unsigned short*)Cp;
#pragma unroll
        for (int i = 0; i < 4; i++)
#pragma unroll
            for (int j = 0; j < 4; j++) {
                int m = m0 + wm * 64 + j * 16 + lr;
#pragma unroll
                for (int r = 0; r < 4; r++) {
                    int n = n0 + wn * 64 + i * 16 + lg * 4 + r;
                    C[(size_t)n * 512 + m] = f2bf(acc[i][j][r] + bs[j]);
                }
            }
    }
}

// ================= radix-8 register FFT (N = 4096 = 8^4) =================
template<int SGN>
__device__ __forceinline__ void radix8(float* xr, float* xi)
{
    const float C = 0.70710678118654752440f;
    const float S = (float)SGN;
    float t0r = xr[0] + xr[4], t0i = xi[0] + xi[4];
    float t1r = xr[1] + xr[5], t1i = xi[1] + xi[5];
    float t2r = xr[2] + xr[6], t2i = xi[2] + xi[6];
    float t3r = xr[3] + xr[7], t3i = xi[3] + xi[7];
    float u0r = xr[0] - xr[4], u0i = xi[0] - xi[4];
    float a1r = xr[1] - xr[5], a1i = xi[1] - xi[5];
    float a2r = xr[2] - xr[6], a2i = xi[2] - xi[6];
    float a3r = xr[3] - xr[7], a3i = xi[3] - xi[7];
    float u1r = C * (a1r - S * a1i), u1i = C * (S * a1r + a1i);
    float u2r = -S * a2i,             u2i = S * a2r;
    float u3r = -C * (a3r + S * a3i), u3i = C * (S * a3r - a3i);
    float v0r = t0r + t2r, v0i = t0i + t2i;
    float w0r = t0r - t2r, w0i = t0i - t2i;
    float v1r = t1r + t3r, v1i = t1i + t3i;
    float w1r = -S * (t1i - t3i), w1i = S * (t1r - t3r);
    float p0r = u0r + u2r, p0i = u0i + u2i;
    float q0r = u0r - u2r, q0i = u0i - u2i;
    float p1r = u1r + u3r, p1i = u1i + u3i;
    float q1r = -S * (u1i - u3i), q1i = S * (u1r - u3r);
    xr[0] = v0r + v1r; xi[0] = v0i + v1i;
    xr[4] = v0r - v1r; xi[4] = v0i - v1i;
    xr[2] = w0r + w1r; xi[2] = w0i + w1i;
    xr[6] = w0r - w1r; xi[6] = w0i - w1i;
    xr[1] = p0r + p1r; xi[1] = p0i + p1i;
    xr[5] = p0r - p1r; xi[5] = p0i - p1i;
    xr[3] = q0r + q1r; xi[3] = q0i + q1i;
    xr[7] = q0r - q1r; xi[7] = q0i - q1i;
}

__device__ __forceinline__ void twmul(float& xr, float& xi, float wc, float ws)
{
    float a = xr, b = xi;
    xr = a * wc - b * ws;
    xi = a * ws + b * wc;
}

__device__ __forceinline__ void twiddle7(float* xr, float* xi, int n, float ang)
{
    float s1, c1;
    __sincosf(ang * (float)n, &s1, &c1);
    float wc = c1, ws = s1;
    twmul(xr[1], xi[1], wc, ws);
#pragma unroll
    for (int r = 2; r < 8; r++) {
        float nc = wc * c1 - ws * s1;
        float ns = wc * s1 + ws * c1;
        wc = nc; ws = ns;
        twmul(xr[r], xi[r], wc, ws);
    }
}

#define SW(i) ((i) + ((i) >> 3))

template<int SGN>
__device__ __forceinline__ void fft_core(float* xr, float* xi,
                                         float* lre, float* lim, int tid)
{
    const float TW = (float)SGN * 6.28318530717958647693f;
    __syncthreads();
    radix8<SGN>(xr, xi);
    twiddle7(xr, xi, tid, TW / 4096.f);
#pragma unroll
    for (int r = 0; r < 8; r++) {
        int idx = r * 512 + tid;
        lre[SW(idx)] = xr[r]; lim[SW(idx)] = xi[r];
    }
    __syncthreads();
    const int b2 = (tid >> 6) * 512, n2 = tid & 63;
#pragma unroll
    for (int s = 0; s < 8; s++) {
        int idx = b2 + n2 + s * 64;
        xr[s] = lre[SW(idx)]; xi[s] = lim[SW(idx)];
    }
    __syncthreads();
    radix8<SGN>(xr, xi);
    twiddle7(xr, xi, n2, TW / 512.f);
#pragma unroll
    for (int r = 0; r < 8; r++) {
        int idx = b2 + r * 64 + n2;
        lre[SW(idx)] = xr[r]; lim[SW(idx)] = xi[r];
    }
    __syncthreads();
    const int b3 = (tid >> 3) * 64, n3 = tid & 7;
#pragma unroll
    for (int s = 0; s < 8; s++) {
        int idx = b3 + n3 + s * 8;
        xr[s] = lre[SW(idx)]; xi[s] = lim[SW(idx)];
    }
    __syncthreads();
    radix8<SGN>(xr, xi);
    twiddle7(xr, xi, n3, TW / 64.f);
#pragma unroll
    for (int r = 0; r < 8; r++) {
        int idx = b3 + r * 8 + n3;
        lre[SW(idx)] = xr[r]; lim[SW(idx)] = xi[r];
    }
    __syncthreads();
#pragma unroll
    for (int s = 0; s < 8; s++) {
        int idx = tid * 8 + s;
        xr[s] = lre[SW(idx)]; xi[s] = lim[SW(idx)];
    }
    __syncthreads();
    radix8<SGN>(xr, xi);
    const int fr = ((tid & 7) << 6) | (((tid >> 3) & 7) << 3) | (tid >> 6);
#pragma unroll
    for (int r = 0; r < 8; r++) {
        int f = r * 512 + fr;
        lre[SW(f)] = xr[r]; lim[SW(f)] = xi[r];
    }
    __syncthreads();
}

// ------- forward FFT of hidden: 2 packed FFTs (4 channels)/block -------
// Z layout: [kb=e>>2][row][4], row = (b*2+plane)*F2 + f  (plane: 0=Re, 1=Im)
__global__ __launch_bounds__(512) void fft_fwd_z(const float* __restrict__ Htr,
                                                 unsigned short* __restrict__ Zh,
                                                 unsigned short* __restrict__ Zl)
{
    __shared__ float lre[4608];
    __shared__ float lim[4608];
    const int bid = blockIdx.x;          // 0..511
    const int tid = threadIdx.x;
    const int b = bid >> 7;
    const int e0 = (bid & 127) * 4;
    const int kbi = e0 >> 2;
    unsigned uh[4][2][2], ul[4][2][2];   // [s][plane][p]
#pragma unroll
    for (int p = 0; p < 2; p++) {
        const float* he = Htr + ((size_t)(b * 512 + e0 + 2 * p)) * 4096;
        const float* ho = Htr + ((size_t)(b * 512 + e0 + 2 * p + 1)) * 4096;
        float xr[8], xi[8];
#pragma unroll
        for (int s = 0; s < 8; s++) {
            xr[s] = he[tid + 512 * s];
            xi[s] = ho[tid + 512 * s];
        }
        fft_core<-1>(xr, xi, lre, lim, tid);
#pragma unroll
        for (int s = 0; s < 4; s++) {
            int f = tid + 512 * s;
            int nf = (4096 - f) & 4095;
            float Ax = lre[SW(f)],  Ay = lim[SW(f)];
            float Bx = lre[SW(nf)], By = lim[SW(nf)];
            float qx = 0.5f * (Ax + Bx), qy = 0.5f * (Ay - By);   // even chan Re,Im
            float kx = 0.5f * (Ay + By), ky = -0.5f * (Ax - Bx);  // odd chan Re,Im
            unsigned short h0 = f2bf(qx), h1 = f2bf(kx);
            uh[s][0][p] = (unsigned)h0 | ((unsigned)h1 << 16);
            ul[s][0][p] = (unsigned)f2bf(qx - bf2f(h0)) | ((unsigned)f2bf(kx - bf2f(h1)) << 16);
            unsigned short h2 = f2bf(qy), h3 = f2bf(ky);
            uh[s][1][p] = (unsigned)h2 | ((unsigned)h3 << 16);
            ul[s][1][p] = (unsigned)f2bf(qy - bf2f(h2)) | ((unsigned)f2bf(ky - bf2f(h3)) << 16);
        }
        if (tid == 0) {
            // f = 2048: unpack degenerates to Re-only; Im plane = 0
            float Ax = lre[SW(2048)], Ay = lim[SW(2048)];
            size_t row0 = (size_t)(b * 2) * F2 + 2048;
            size_t off0 = ((size_t)kbi * ZROWS + row0) * 4 + 2 * p;
            unsigned short h = f2bf(Ax);
            Zh[off0] = h; Zl[off0] = f2bf(Ax - bf2f(h));
            unsigned short h2 = f2bf(Ay);
            Zh[off0 + 1] = h2; Zl[off0 + 1] = f2bf(Ay - bf2f(h2));
            size_t off1 = ((size_t)kbi * ZROWS + row0 + F2) * 4 + 2 * p;
            Zh[off1] = 0; Zl[off1] = 0;
            Zh[off1 + 1] = 0; Zl[off1 + 1] = 0;
        }
    }
#pragma unroll
    for (int s = 0; s < 4; s++)
#pragma unroll
        for (int c = 0; c < 2; c++) {
            size_t row = (size_t)(b * 2 + c) * F2 + tid + 512 * s;
            size_t off = ((size_t)kbi * ZROWS + row) * 4;
            ushort4 vh = make_ushort4((unsigned short)(uh[s][c][0] & 0xffff),
                                      (unsigned short)(uh[s][c][0] >> 16),
                                      (unsigned short)(uh[s][c][1] & 0xffff),
                                      (unsigned short)(uh[s][c][1] >> 16));
            ushort4 vl = make_ushort4((unsigned short)(ul[s][c][0] & 0xffff),
                                      (unsigned short)(ul[s][c][0] >> 16),
                                      (unsigned short)(ul[s][c][1] & 0xffff),
                                      (unsigned short)(ul[s][c][1] >> 16));
            *(ushort4*)&Zh[off] = vh;
            *(ushort4*)&Zl[off] = vl;
        }
}

// ------- S[b,f] = sum_e Y[row,e] * conj(z[e])  (rows plane-major) -------
__global__ __launch_bounds__(256) void dot_s(const float* __restrict__ Y,
                                             const unsigned short* __restrict__ Zh,
                                             const unsigned short* __restrict__ Zl,
                                             float2* __restrict__ S)
{
    const int f = blockIdx.x * 256 + threadIdx.x;
    const int b = blockIdx.y;
    if (f > 2048) return;
    const size_t row_re = (size_t)(b * 2) * F2 + f;
    const size_t row_im = row_re + F2;
    float sre = 0.f, sim = 0.f;
    for (int kb = 0; kb < 128; kb++) {
        size_t zr_off = ((size_t)kb * ZROWS + row_re) * 4;
        size_t zi_off = ((size_t)kb * ZROWS + row_im) * 4;
        bf16x4 zrh = *(const bf16x4*)&Zh[zr_off];
        bf16x4 zrl = *(const bf16x4*)&Zl[zr_off];
        bf16x4 zih = *(const bf16x4*)&Zh[zi_off];
        bf16x4 zil = *(const bf16x4*)&Zl[zi_off];
        float4 yr = *(const float4*)&Y[row_re * 512 + kb * 4];
        float4 yi = *(const float4*)&Y[row_im * 512 + kb * 4];
        float yrv[4] = {yr.x, yr.y, yr.z, yr.w};
        float yiv[4] = {yi.x, yi.y, yi.z, yi.w};
#pragma unroll
        for (int j = 0; j < 4; j++) {
            float zr = bf2f((unsigned short)zrh[j]) + bf2f((unsigned short)zrl[j]);
            float zi = bf2f((unsigned short)zih[j]) + bf2f((unsigned short)zil[j]);
            sre += yrv[j] * zr + yiv[j] * zi;
            sim += yiv[j] * zr - yrv[j] * zi;
        }
    }
    S[b * FHP + f] = make_float2(sre, sim);
}

// ---------------- inverse FFT -> ac_mean ----------------
__global__ __launch_bounds__(512) void ifft_kernel(const float2* __restrict__ S,
                                                   float* __restrict__ acm)
{
    __shared__ float lre[4608];
    __shared__ float lim[4608];
    const int b = blockIdx.x, tid = threadIdx.x;
    float xr[8], xi[8];
#pragma unroll
    for (int s = 0; s < 8; s++) {
        int idx = tid + 512 * s;
        if (idx <= 2048) {
            float2 v = S[b * FHP + idx];
            xr[s] = v.x; xi[s] = v.y;
        } else {
            float2 v = S[b * FHP + (4096 - idx)];
            xr[s] = v.x; xi[s] = -v.y;
        }
    }
    fft_core<1>(xr, xi, lre, lim, tid);
    const float scale = 1.0f / ((float)T_ * (float)E_);
#pragma unroll
    for (int s = 0; s < 8; s++) {
        int p = tid + 512 * s;
        acm[b * T_ + p] = lre[SW(p)] * scale;
    }
}

// ---------------- top-k (24) + softmax, per batch ----------------
__global__ __launch_bounds__(256) void topk_kernel(const float* __restrict__ acm,
                                                   int* __restrict__ delays,
                                                   float* __restrict__ weights)
{
    __shared__ float vals[4096];
    __shared__ float bv[256];
    __shared__ int   bi[256];
    __shared__ float topv[TOPK];
    const int b = blockIdx.x, tid = threadIdx.x;
#pragma unroll
    for (int s = 0; s < 16; s++) vals[tid + 256 * s] = acm[b * T_ + tid + 256 * s];
    __syncthreads();
    for (int it = 0; it < TOPK; it++) {
        float best = -INFINITY; int bidx = 0;
#pragma unroll
        for (int s = 0; s < 16; s++) {
            int idx = tid * 16 + s;
            float v = vals[idx];
            if (v > best) { best = v; bidx = idx; }
        }
        bv[tid] = best; bi[tid] = bidx;
        __syncthreads();
        for (int off = 128; off > 0; off >>= 1) {
            if (tid < off) {
                if (bv[tid + off] > bv[tid] ||
                    (bv[tid + off] == bv[tid] && bi[tid + off] < bi[tid])) {
                    bv[tid] = bv[tid + off]; bi[tid] = bi[tid + off];
                }
            }
            __syncthreads();
        }
        if (tid == 0) {
            delays[b * TOPK + it] = bi[0];
            topv[it] = bv[0];
            vals[bi[0]] = -INFINITY;
        }
        __syncthreads();
    }
    if (tid == 0) {
        float mx = topv[0];
        float w[TOPK], sum = 0.f;
        for (int i = 0; i < TOPK; i++) { w[i] = expf(topv[i] - mx); sum += w[i]; }
        for (int i = 0; i < TOPK; i++) weights[b * TOPK + i] = w[i] / sum;
    }
}

// ---------------- agg: weighted circular gather of bf16 V ----------------
__global__ __launch_bounds__(256) void agg_kernel(const unsigned short* __restrict__ V,
                                                  const int* __restrict__ delays,
                                                  const float* __restrict__ wts,
                                                  unsigned short* __restrict__ agg)
{
    __shared__ int   dly[B_][TOPK];
    __shared__ float wt[B_][TOPK];
    const int tid = threadIdx.x, b = blockIdx.y;
    if (tid < B_ * TOPK) {
        dly[tid / TOPK][tid % TOPK] = delays[tid];
        wt[tid / TOPK][tid % TOPK]  = wts[tid];
    }
    __syncthreads();
    const int lane = tid & 63, w = tid >> 6;
    const int t = blockIdx.x * 4 + w;
    const int e8 = lane * 8;
    const int h = e8 >> 6;
    const int c = (b * H_ + h) % B_;
    const unsigned short* Vb = V + (size_t)b * T_ * E_;
    float acc[8];
#pragma unroll
    for (int j = 0; j < 8; j++) acc[j] = 0.f;
#pragma unroll
    for (int i = 0; i < TOPK; i++) {
        int tt = (t + dly[c][i]) & (T_ - 1);
        bf16x8 v = *(const bf16x8*)&Vb[(size_t)tt * E_ + e8];
        float wg = wt[c][i];
#pragma unroll
        for (int j = 0; j < 8; j++)
            acc[j] += wg * bf2f((unsigned short)v[j]);
    }
    bf16x8 o;
#pragma unroll
    for (int j = 0; j < 8; j++) o[j] = (short)f2bf(acc[j]);
    *(bf16x8*)&agg[((size_t)b * T_ + t) * E_ + e8] = o;
}

// ---------------- launch ----------------
extern "C" void kernel_launch(void* const* d_in, const int* in_sizes, int n_in,
                              void* d_out, int out_size, void* d_ws, size_t ws_size,
                              hipStream_t stream)
{
    const float* hidden = (const float*)d_in[0];
    const float* Wq = (const float*)d_in[1];
    const float* Wk = (const float*)d_in[3];
    const float* Wv = (const float*)d_in[5]; const float* bv = (const float*)d_in[6];
    const float* Wo = (const float*)d_in[7]; const float* bo = (const float*)d_in[8];

    char* ws = (char*)d_ws;
    const size_t YA_OFF  = 0;                  // 33.8 MB: Htr fp32, later Y fp32
    const size_t AH_OFF  = 33816576;           // 16.8 MB: Ah bf16, later Ag bf16
    const size_t ZH_OFF  = 50593792;           // 16.9 MB
    const size_t ZL_OFF  = 67502080;           // 16.9 MB
    const size_t VB_OFF  = 84410368;           // 16.8 MB: Mp partials, then Vb bf16
    const size_t MTH_OFF = 101187584;          // 512 KB
    const size_t MTL_OFF = 101711872;          // 512 KB
    const size_t WVH_OFF = 102236160;          // 512 KB
    const size_t WOH_OFF = 102760448;          // 512 KB
    const size_t S_OFF   = 103284736;          // 66 KB
    const size_t ACM_OFF = 103350784;          // 64 KB
    const size_t DEL_OFF = 103416320;          // 384 B
    const size_t WTS_OFF = 103416704;          // 384 B
    if (ws_size < 103417088) return;

    float* Htr = (float*)(ws + YA_OFF);
    float* Y   = (float*)(ws + YA_OFF);
    unsigned short* Ah  = (unsigned short*)(ws + AH_OFF);
    unsigned short* Ag  = (unsigned short*)(ws + AH_OFF);
    unsigned short* Zh  = (unsigned short*)(ws + ZH_OFF);
    unsigned short* Zl  = (unsigned short*)(ws + ZL_OFF);
    float* Mp           = (float*)(ws + VB_OFF);
    unsigned short* Vb  = (unsigned short*)(ws + VB_OFF);
    unsigned short* Mth = (unsigned short*)(ws + MTH_OFF);
    unsigned short* Mtl = (unsigned short*)(ws + MTL_OFF);
    unsigned short* Wvh = (unsigned short*)(ws + WVH_OFF);
    unsigned short* Woh = (unsigned short*)(ws + WOH_OFF);
    float2* S    = (float2*)(ws + S_OFF);
    float*  acm  = (float*)(ws + ACM_OFF);
    int*    delays = (int*)(ws + DEL_OFF);
    float*  wts    = (float*)(ws + WTS_OFF);

    // prep: transpose+split hidden; split Wv/Wo; M = Wq^T Wk via split-K partials
    dim3 tg(64, 8, 4);
    trsp_split<<<tg, 256, 0, stream>>>(hidden, Htr, Ah);
    dim3 swg(256, 2);
    split_w2<<<swg, 256, 0, stream>>>(Wv, Wo, Wvh, Woh);
    dim3 mg(4, 4, 16);
    wprep_partial<<<mg, 256, 0, stream>>>(Wq, Wk, Mp);
    reduce_split_m<<<256, 256, 0, stream>>>(Mp, Mth, Mtl);   // 512*512/(256*4) = 256 blocks

    // V GEMM (bf16 out) — overwrites Mp region (dead after reduce)
    dim3 gv(4, 128);
    mfma_gemm<1, 0, 2, 1><<<gv, 256, 0, stream>>>(Ah, Ah, Wvh, Wvh, bv, Vb);

    // FFT of hidden -> split Z — frees Htr afterwards
    fft_fwd_z<<<512, 512, 0, stream>>>(Htr, Zh, Zl);

    // Y = Z * M^T (3-pass split), fp32 out into Htr-space
    dim3 gy(4, 129);
    mfma_gemm<3, 1, 0, 0><<<gy, 256, 0, stream>>>(Zh, Zl, Mth, Mtl, bv, Y);

    // S[b,f] = row-dot(Y, conj(Z))
    dim3 dg(9, 4);
    dot_s<<<dg, 256, 0, stream>>>(Y, Zh, Zl, S);

    // ac_mean, top-k, weighted gather, output projection
    ifft_kernel<<<B_, 512, 0, stream>>>(S, acm);
    topk_kernel<<<B_, 256, 0, stream>>>(acm, delays, wts);
    dim3 ag(T_ / 4, B_);
    agg_kernel<<<ag, 256, 0, stream>>>(Vb, delays, wts, Ag);
    mfma_gemm<1, 0, 0, 1><<<gv, 256, 0, stream>>>(Ag, Ag, Woh, Woh, bo, (float*)d_out);
}

// Round 7
// 285.378 us; speedup vs baseline: 1.2017x; 1.0873x over previous
//
#include <hip/hip_runtime.h>
#include <math.h>

#define B_ 4
#define T_ 4096
#define E_ 512
#define H_ 8
#define TOPK 24
#define FH 2049
#define FHP 2064
#define F2 2064
#define ZROWS 16512   // B * 2 * F2  (plane-major: row = (b*2+plane)*F2 + f)

typedef __attribute__((ext_vector_type(8))) short bf16x8;
typedef __attribute__((ext_vector_type(4))) short bf16x4;
typedef __attribute__((ext_vector_type(4))) float f32x4;

__device__ __forceinline__ unsigned short f2bf(float f) {
    unsigned u = __float_as_uint(f);
    u = (u + 0x7FFFu + ((u >> 16) & 1u)) >> 16;
    return (unsigned short)u;
}
__device__ __forceinline__ float bf2f(unsigned short h) {
    return __uint_as_float(((unsigned)h) << 16);
}

// ------- transpose hidden [B,T,E]->[B,E,T] fp32 + bf16 (hi) natural -------
__global__ __launch_bounds__(256) void trsp_split(const float* __restrict__ hid,
                                                  float* __restrict__ Htr,
                                                  unsigned short* __restrict__ Ah)
{
    __shared__ float tile[64][68];
    const int b = blockIdx.z;
    const int t0 = blockIdx.x * 64, e0 = blockIdx.y * 64;
    const int r = threadIdx.x >> 4;
    const int c4 = (threadIdx.x & 15) * 4;
#pragma unroll
    for (int s = 0; s < 4; s++) {
        int t = t0 + r + 16 * s;
        float4 v = *(const float4*)&hid[((size_t)b * T_ + t) * E_ + e0 + c4];
        tile[r + 16 * s][c4 + 0] = v.x; tile[r + 16 * s][c4 + 1] = v.y;
        tile[r + 16 * s][c4 + 2] = v.z; tile[r + 16 * s][c4 + 3] = v.w;
        ushort4 hv = make_ushort4(f2bf(v.x), f2bf(v.y), f2bf(v.z), f2bf(v.w));
        *(ushort4*)&Ah[((size_t)b * T_ + t) * E_ + e0 + c4] = hv;
    }
    __syncthreads();
#pragma unroll
    for (int s = 0; s < 4; s++) {
        int e = e0 + r + 16 * s;
        float4 o;
        o.x = tile[c4 + 0][r + 16 * s];
        o.y = tile[c4 + 1][r + 16 * s];
        o.z = tile[c4 + 2][r + 16 * s];
        o.w = tile[c4 + 3][r + 16 * s];
        *(float4*)&Htr[((size_t)b * E_ + e) * T_ + t0 + c4] = o;
    }
}

// ------- split Wv, Wo to bf16 hi -------
__global__ __launch_bounds__(256) void split_w2(const float* __restrict__ wv,
                                                const float* __restrict__ wo,
                                                unsigned short* __restrict__ Wvh,
                                                unsigned short* __restrict__ Woh)
{
    const float* src = blockIdx.y ? wo : wv;
    unsigned short* dst = blockIdx.y ? Woh : Wvh;
    int i = (blockIdx.x * 256 + threadIdx.x) * 4;
    float4 v = *(const float4*)&src[i];
    *(ushort4*)&dst[i] = make_ushort4(f2bf(v.x), f2bf(v.y), f2bf(v.z), f2bf(v.w));
}

// ------- M^T partials: Mp[z][j][k] = sum_{e in chunk z} Wq[e,k]*Wk[e,j] -------
__global__ __launch_bounds__(256) void wprep_partial(const float* __restrict__ Wq,
                                                     const float* __restrict__ Wk,
                                                     float* __restrict__ Mp)
{
    __shared__ float As[8][132];
    __shared__ float Bs[8][132];
    const int j0 = blockIdx.x * 128, k0 = blockIdx.y * 128;
    const int e0 = blockIdx.z * 32;
    const int tid = threadIdx.x;
    const int tm = tid & 15, tn = tid >> 4;
    const int le = tid >> 5, lc = (tid & 31) * 4;
    float acc[8][8];
#pragma unroll
    for (int i = 0; i < 8; i++)
#pragma unroll
        for (int j = 0; j < 8; j++) acc[i][j] = 0.f;
    for (int eb = e0; eb < e0 + 32; eb += 8) {
        __syncthreads();
        *(float4*)&As[le][lc] = *(const float4*)&Wq[((size_t)(eb + le)) * 512 + k0 + lc];
        *(float4*)&Bs[le][lc] = *(const float4*)&Wk[((size_t)(eb + le)) * 512 + j0 + lc];
        __syncthreads();
#pragma unroll
        for (int e = 0; e < 8; e++) {
            float a[8], bb[8];
            *(float4*)&a[0] = *(float4*)&As[e][4 * tn];
            *(float4*)&a[4] = *(float4*)&As[e][64 + 4 * tn];
            *(float4*)&bb[0] = *(float4*)&Bs[e][4 * tm];
            *(float4*)&bb[4] = *(float4*)&Bs[e][64 + 4 * tm];
#pragma unroll
            for (int i = 0; i < 8; i++)
#pragma unroll
                for (int j = 0; j < 8; j++)
                    acc[i][j] += a[i] * bb[j];
        }
    }
    float* out = Mp + (size_t)blockIdx.z * 512 * 512;
#pragma unroll
    for (int jj = 0; jj < 8; jj++) {
        int j = j0 + ((jj < 4) ? (4 * tm + jj) : (64 + 4 * tm + jj - 4));
        float4 o0 = make_float4(acc[0][jj], acc[1][jj], acc[2][jj], acc[3][jj]);
        float4 o1 = make_float4(acc[4][jj], acc[5][jj], acc[6][jj], acc[7][jj]);
        *(float4*)&out[(size_t)j * 512 + k0 + 4 * tn] = o0;
        *(float4*)&out[(size_t)j * 512 + k0 + 64 + 4 * tn] = o1;
    }
}

// ------- reduce 16 partials, split to bf16 hi/lo (262144 elements total) -------
__global__ __launch_bounds__(256) void reduce_split_m(const float* __restrict__ Mp,
                                                      unsigned short* __restrict__ Mth,
                                                      unsigned short* __restrict__ Mtl)
{
    int i = (blockIdx.x * 256 + threadIdx.x) * 4;
    if (i >= 512 * 512) return;          // geometry guard
    float4 s = make_float4(0.f, 0.f, 0.f, 0.f);
#pragma unroll
    for (int z = 0; z < 16; z++) {
        float4 v = *(const float4*)&Mp[(size_t)z * 262144 + i];
        s.x += v.x; s.y += v.y; s.z += v.z; s.w += v.w;
    }
    float f[4] = {s.x, s.y, s.z, s.w};
    unsigned short hh[4], ll[4];
#pragma unroll
    for (int r = 0; r < 4; r++) {
        hh[r] = f2bf(f[r]);
        ll[r] = f2bf(f[r] - bf2f(hh[r]));
    }
    *(ushort4*)&Mth[i] = make_ushort4(hh[0], hh[1], hh[2], hh[3]);
    *(ushort4*)&Mtl[i] = make_ushort4(ll[0], ll[1], ll[2], ll[3]);
}

// ---------------- MFMA GEMM: C[n,m] = sum_k A[n,k]*B[m,k] (+ bias[m]) ----------------
// Tile 128n x 64m, BK=32, 256 thr (4 waves as 2n x 2m), grid (M/64, N/128).
// PASSES: 1 or 3.  AMODE: 0 = row-major [N,512], 1 = Z layout [kb][row][4].
// OMODE: 0 = fp32 [N,512], 2 = bf16 [N,512].  HASBIAS: 0/1.
template<int PASSES, int AMODE, int OMODE, int HASBIAS>
__global__ __launch_bounds__(256) void mfma_gemm(const unsigned short* __restrict__ Ah,
                                                 const unsigned short* __restrict__ Al,
                                                 const unsigned short* __restrict__ Bh,
                                                 const unsigned short* __restrict__ Bl,
                                                 const float* __restrict__ bias,
                                                 void* __restrict__ Cp)
{
    constexpr int ATS = 128 * 40;
    constexpr int BTS = 64 * 40;
    constexpr int TOT = (PASSES == 3) ? 2 * (ATS + BTS) : (ATS + BTS);
    __shared__ short smem[TOT];
    short* At  = smem;
    short* Alt = smem + ((PASSES == 3) ? ATS : 0);
    short* Bt  = smem + ((PASSES == 3) ? 2 * ATS : ATS);
    short* Blt = Bt + ((PASSES == 3) ? BTS : 0);

    const int tid = threadIdx.x;
    const int m0 = blockIdx.x * 64;
    const int n0 = blockIdx.y * 128;
    const int wid = tid >> 6, lane = tid & 63;
    const int wn = wid >> 1, wm = wid & 1;
    const int lr = lane & 15, lg = lane >> 4;
    const int kb = lg * 8;

    f32x4 acc[4][2];
#pragma unroll
    for (int i = 0; i < 4; i++)
#pragma unroll
        for (int j = 0; j < 2; j++) acc[i][j] = (f32x4)0.f;

    const int r0 = tid >> 2, kp = (tid & 3) << 3;

    for (int k0 = 0; k0 < 512; k0 += 32) {
        __syncthreads();
        if (AMODE == 0) {
            size_t a0 = (size_t)(n0 + r0) * 512 + k0 + kp;
            size_t a1 = (size_t)(n0 + r0 + 64) * 512 + k0 + kp;
            *(bf16x8*)&At[r0 * 40 + kp]        = *(const bf16x8*)&Ah[a0];
            *(bf16x8*)&At[(r0 + 64) * 40 + kp] = *(const bf16x8*)&Ah[a1];
            if (PASSES == 3) {
                *(bf16x8*)&Alt[r0 * 40 + kp]        = *(const bf16x8*)&Al[a0];
                *(bf16x8*)&Alt[(r0 + 64) * 40 + kp] = *(const bf16x8*)&Al[a1];
            }
        } else {
            size_t za = (size_t)((k0 + kp) >> 2) * ZROWS;
            const size_t st = (size_t)ZROWS * 4;
            size_t a0 = (za + n0 + r0) * 4;
            size_t a1 = (za + n0 + r0 + 64) * 4;
            *(bf16x4*)&At[r0 * 40 + kp]            = *(const bf16x4*)&Ah[a0];
            *(bf16x4*)&At[r0 * 40 + kp + 4]        = *(const bf16x4*)&Ah[a0 + st];
            *(bf16x4*)&At[(r0 + 64) * 40 + kp]     = *(const bf16x4*)&Ah[a1];
            *(bf16x4*)&At[(r0 + 64) * 40 + kp + 4] = *(const bf16x4*)&Ah[a1 + st];
            if (PASSES == 3) {
                *(bf16x4*)&Alt[r0 * 40 + kp]            = *(const bf16x4*)&Al[a0];
                *(bf16x4*)&Alt[r0 * 40 + kp + 4]        = *(const bf16x4*)&Al[a0 + st];
                *(bf16x4*)&Alt[(r0 + 64) * 40 + kp]     = *(const bf16x4*)&Al[a1];
                *(bf16x4*)&Alt[(r0 + 64) * 40 + kp + 4] = *(const bf16x4*)&Al[a1 + st];
            }
        }
        size_t bb = (size_t)(m0 + r0) * 512 + k0 + kp;
        *(bf16x8*)&Bt[r0 * 40 + kp] = *(const bf16x8*)&Bh[bb];
        if (PASSES == 3)
            *(bf16x8*)&Blt[r0 * 40 + kp] = *(const bf16x8*)&Bl[bb];
        __syncthreads();

        bf16x8 a[4], b[2];
#pragma unroll
        for (int f = 0; f < 4; f++)
            a[f] = *(bf16x8*)&At[(wn * 64 + f * 16 + lr) * 40 + kb];
#pragma unroll
        for (int j = 0; j < 2; j++)
            b[j] = *(bf16x8*)&Bt[(wm * 32 + j * 16 + lr) * 40 + kb];
        if (PASSES == 3) {
            bf16x8 a2[4], b2[2];
#pragma unroll
            for (int f = 0; f < 4; f++)
                a2[f] = *(bf16x8*)&Alt[(wn * 64 + f * 16 + lr) * 40 + kb];
#pragma unroll
            for (int j = 0; j < 2; j++)
                b2[j] = *(bf16x8*)&Blt[(wm * 32 + j * 16 + lr) * 40 + kb];
#pragma unroll
            for (int i = 0; i < 4; i++)
#pragma unroll
                for (int j = 0; j < 2; j++) {
                    acc[i][j] = __builtin_amdgcn_mfma_f32_16x16x32_bf16(a[i], b[j], acc[i][j], 0, 0, 0);
                    acc[i][j] = __builtin_amdgcn_mfma_f32_16x16x32_bf16(a[i], b2[j], acc[i][j], 0, 0, 0);
                    acc[i][j] = __builtin_amdgcn_mfma_f32_16x16x32_bf16(a2[i], b[j], acc[i][j], 0, 0, 0);
                }
        } else {
#pragma unroll
            for (int i = 0; i < 4; i++)
#pragma unroll
                for (int j = 0; j < 2; j++)
                    acc[i][j] = __builtin_amdgcn_mfma_f32_16x16x32_bf16(a[i], b[j], acc[i][j], 0, 0, 0);
        }
    }

    float bs[2];
#pragma unroll
    for (int j = 0; j < 2; j++) bs[j] = HASBIAS ? bias[m0 + wm * 32 + j * 16 + lr] : 0.f;

    if (OMODE == 0) {
        float* C = (float*)Cp;
#pragma unroll
        for (int i = 0; i < 4; i++)
#pragma unroll
            for (int j = 0; j < 2; j++) {
                int m = m0 + wm * 32 + j * 16 + lr;
#pragma unroll
                for (int r = 0; r < 4; r++) {
                    int n = n0 + wn * 64 + i * 16 + lg * 4 + r;
                    C[(size_t)n * 512 + m] = acc[i][j][r] + bs[j];
                }
            }
    } else {
        unsigned short* C = (unsigned short*)Cp;
#pragma unroll
        for (int i = 0; i < 4; i++)
#pragma unroll
            for (int j = 0; j < 2; j++) {
                int m = m0 + wm * 32 + j * 16 + lr;
#pragma unroll
                for (int r = 0; r < 4; r++) {
                    int n = n0 + wn * 64 + i * 16 + lg * 4 + r;
                    C[(size_t)n * 512 + m] = f2bf(acc[i][j][r] + bs[j]);
                }
            }
    }
}

// ================= radix-8 register FFT (N = 4096 = 8^4) =================
template<int SGN>
__device__ __forceinline__ void radix8(float* xr, float* xi)
{
    const float C = 0.70710678118654752440f;
    const float S = (float)SGN;
    float t0r = xr[0] + xr[4], t0i = xi[0] + xi[4];
    float t1r = xr[1] + xr[5], t1i = xi[1] + xi[5];
    float t2r = xr[2] + xr[6], t2i = xi[2] + xi[6];
    float t3r = xr[3] + xr[7], t3i = xi[3] + xi[7];
    float u0r = xr[0] - xr[4], u0i = xi[0] - xi[4];
    float a1r = xr[1] - xr[5], a1i = xi[1] - xi[5];
    float a2r = xr[2] - xr[6], a2i = xi[2] - xi[6];
    float a3r = xr[3] - xr[7], a3i = xi[3] - xi[7];
    float u1r = C * (a1r - S * a1i), u1i = C * (S * a1r + a1i);
    float u2r = -S * a2i,             u2i = S * a2r;
    float u3r = -C * (a3r + S * a3i), u3i = C * (S * a3r - a3i);
    float v0r = t0r + t2r, v0i = t0i + t2i;
    float w0r = t0r - t2r, w0i = t0i - t2i;
    float v1r = t1r + t3r, v1i = t1i + t3i;
    float w1r = -S * (t1i - t3i), w1i = S * (t1r - t3r);
    float p0r = u0r + u2r, p0i = u0i + u2i;
    float q0r = u0r - u2r, q0i = u0i - u2i;
    float p1r = u1r + u3r, p1i = u1i + u3i;
    float q1r = -S * (u1i - u3i), q1i = S * (u1r - u3r);
    xr[0] = v0r + v1r; xi[0] = v0i + v1i;
    xr[4] = v0r - v1r; xi[4] = v0i - v1i;
    xr[2] = w0r + w1r; xi[2] = w0i + w1i;
    xr[6] = w0r - w1r; xi[6] = w0i - w1i;
    xr[1] = p0r + p1r; xi[1] = p0i + p1i;
    xr[5] = p0r - p1r; xi[5] = p0i - p1i;
    xr[3] = q0r + q1r; xi[3] = q0i + q1i;
    xr[7] = q0r - q1r; xi[7] = q0i - q1i;
}

__device__ __forceinline__ void twmul(float& xr, float& xi, float wc, float ws)
{
    float a = xr, b = xi;
    xr = a * wc - b * ws;
    xi = a * ws + b * wc;
}

__device__ __forceinline__ void twiddle7(float* xr, float* xi, int n, float ang)
{
    float s1, c1;
    __sincosf(ang * (float)n, &s1, &c1);
    float wc = c1, ws = s1;
    twmul(xr[1], xi[1], wc, ws);
#pragma unroll
    for (int r = 2; r < 8; r++) {
        float nc = wc * c1 - ws * s1;
        float ns = wc * s1 + ws * c1;
        wc = nc; ws = ns;
        twmul(xr[r], xi[r], wc, ws);
    }
}

#define SW(i) ((i) + ((i) >> 3))

template<int SGN>
__device__ __forceinline__ void fft_core(float* xr, float* xi,
                                         float* lre, float* lim, int tid)
{
    const float TW = (float)SGN * 6.28318530717958647693f;
    __syncthreads();
    radix8<SGN>(xr, xi);
    twiddle7(xr, xi, tid, TW / 4096.f);
#pragma unroll
    for (int r = 0; r < 8; r++) {
        int idx = r * 512 + tid;
        lre[SW(idx)] = xr[r]; lim[SW(idx)] = xi[r];
    }
    __syncthreads();
    const int b2 = (tid >> 6) * 512, n2 = tid & 63;
#pragma unroll
    for (int s = 0; s < 8; s++) {
        int idx = b2 + n2 + s * 64;
        xr[s] = lre[SW(idx)]; xi[s] = lim[SW(idx)];
    }
    __syncthreads();
    radix8<SGN>(xr, xi);
    twiddle7(xr, xi, n2, TW / 512.f);
#pragma unroll
    for (int r = 0; r < 8; r++) {
        int idx = b2 + r * 64 + n2;
        lre[SW(idx)] = xr[r]; lim[SW(idx)] = xi[r];
    }
    __syncthreads();
    const int b3 = (tid >> 3) * 64, n3 = tid & 7;
#pragma unroll
    for (int s = 0; s < 8; s++) {
        int idx = b3 + n3 + s * 8;
        xr[s] = lre[SW(idx)]; xi[s] = lim[SW(idx)];
    }
    __syncthreads();
    radix8<SGN>(xr, xi);
    twiddle7(xr, xi, n3, TW / 64.f);
#pragma unroll
    for (int r = 0; r < 8; r++) {
        int idx = b3 + r * 8 + n3;
        lre[SW(idx)] = xr[r]; lim[SW(idx)] = xi[r];
    }
    __syncthreads();
#pragma unroll
    for (int s = 0; s < 8; s++) {
        int idx = tid * 8 + s;
        xr[s] = lre[SW(idx)]; xi[s] = lim[SW(idx)];
    }
    __syncthreads();
    radix8<SGN>(xr, xi);
    const int fr = ((tid & 7) << 6) | (((tid >> 3) & 7) << 3) | (tid >> 6);
#pragma unroll
    for (int r = 0; r < 8; r++) {
        int f = r * 512 + fr;
        lre[SW(f)] = xr[r]; lim[SW(f)] = xi[r];
    }
    __syncthreads();
}

// ------- forward FFT of hidden: 2 packed FFTs (4 channels)/block -------
// Z layout: [kb=e>>2][row][4], row = (b*2+plane)*F2 + f  (plane: 0=Re, 1=Im)
__global__ __launch_bounds__(512) void fft_fwd_z(const float* __restrict__ Htr,
                                                 unsigned short* __restrict__ Zh,
                                                 unsigned short* __restrict__ Zl)
{
    __shared__ float lre[4608];
    __shared__ float lim[4608];
    const int bid = blockIdx.x;          // 0..511
    const int tid = threadIdx.x;
    const int b = bid >> 7;
    const int e0 = (bid & 127) * 4;
    const int kbi = e0 >> 2;
    unsigned uh[4][2][2], ul[4][2][2];   // [s][plane][p]
#pragma unroll
    for (int p = 0; p < 2; p++) {
        const float* he = Htr + ((size_t)(b * 512 + e0 + 2 * p)) * 4096;
        const float* ho = Htr + ((size_t)(b * 512 + e0 + 2 * p + 1)) * 4096;
        float xr[8], xi[8];
#pragma unroll
        for (int s = 0; s < 8; s++) {
            xr[s] = he[tid + 512 * s];
            xi[s] = ho[tid + 512 * s];
        }
        fft_core<-1>(xr, xi, lre, lim, tid);
#pragma unroll
        for (int s = 0; s < 4; s++) {
            int f = tid + 512 * s;
            int nf = (4096 - f) & 4095;
            float Ax = lre[SW(f)],  Ay = lim[SW(f)];
            float Bx = lre[SW(nf)], By = lim[SW(nf)];
            float qx = 0.5f * (Ax + Bx), qy = 0.5f * (Ay - By);   // even chan Re,Im
            float kx = 0.5f * (Ay + By), ky = -0.5f * (Ax - Bx);  // odd chan Re,Im
            unsigned short h0 = f2bf(qx), h1 = f2bf(kx);
            uh[s][0][p] = (unsigned)h0 | ((unsigned)h1 << 16);
            ul[s][0][p] = (unsigned)f2bf(qx - bf2f(h0)) | ((unsigned)f2bf(kx - bf2f(h1)) << 16);
            unsigned short h2 = f2bf(qy), h3 = f2bf(ky);
            uh[s][1][p] = (unsigned)h2 | ((unsigned)h3 << 16);
            ul[s][1][p] = (unsigned)f2bf(qy - bf2f(h2)) | ((unsigned)f2bf(ky - bf2f(h3)) << 16);
        }
        if (tid == 0) {
            // f = 2048: unpack degenerates; Im plane = 0
            float Ax = lre[SW(2048)], Ay = lim[SW(2048)];
            size_t row0 = (size_t)(b * 2) * F2 + 2048;
            size_t off0 = ((size_t)kbi * ZROWS + row0) * 4 + 2 * p;
            unsigned short h = f2bf(Ax);
            Zh[off0] = h; Zl[off0] = f2bf(Ax - bf2f(h));
            unsigned short h2 = f2bf(Ay);
            Zh[off0 + 1] = h2; Zl[off0 + 1] = f2bf(Ay - bf2f(h2));
            size_t off1 = ((size_t)kbi * ZROWS + row0 + F2) * 4 + 2 * p;
            Zh[off1] = 0; Zl[off1] = 0;
            Zh[off1 + 1] = 0; Zl[off1 + 1] = 0;
        }
    }
#pragma unroll
    for (int s = 0; s < 4; s++)
#pragma unroll
        for (int c = 0; c < 2; c++) {
            size_t row = (size_t)(b * 2 + c) * F2 + tid + 512 * s;
            size_t off = ((size_t)kbi * ZROWS + row) * 4;
            ushort4 vh = make_ushort4((unsigned short)(uh[s][c][0] & 0xffff),
                                      (unsigned short)(uh[s][c][0] >> 16),
                                      (unsigned short)(uh[s][c][1] & 0xffff),
                                      (unsigned short)(uh[s][c][1] >> 16));
            ushort4 vl = make_ushort4((unsigned short)(ul[s][c][0] & 0xffff),
                                      (unsigned short)(ul[s][c][0] >> 16),
                                      (unsigned short)(ul[s][c][1] & 0xffff),
                                      (unsigned short)(ul[s][c][1] >> 16));
            *(ushort4*)&Zh[off] = vh;
            *(ushort4*)&Zl[off] = vl;
        }
}

// ------- Sp[gz][b][f] = sum_{kb in chunk gz} Y[row,4kb..] . conj(z) -------
__global__ __launch_bounds__(256) void dot_s(const float* __restrict__ Y,
                                             const unsigned short* __restrict__ Zh,
                                             const unsigned short* __restrict__ Zl,
                                             float2* __restrict__ Sp)
{
    const int f = blockIdx.x * 256 + threadIdx.x;
    const int b = blockIdx.y;
    const int gz = blockIdx.z;
    if (f > 2048) return;
    const size_t row_re = (size_t)(b * 2) * F2 + f;
    const size_t row_im = row_re + F2;
    float sre = 0.f, sim = 0.f;
    for (int kb = gz * 16; kb < gz * 16 + 16; kb++) {
        size_t zr_off = ((size_t)kb * ZROWS + row_re) * 4;
        size_t zi_off = ((size_t)kb * ZROWS + row_im) * 4;
        bf16x4 zrh = *(const bf16x4*)&Zh[zr_off];
        bf16x4 zrl = *(const bf16x4*)&Zl[zr_off];
        bf16x4 zih = *(const bf16x4*)&Zh[zi_off];
        bf16x4 zil = *(const bf16x4*)&Zl[zi_off];
        float4 yr = *(const float4*)&Y[row_re * 512 + kb * 4];
        float4 yi = *(const float4*)&Y[row_im * 512 + kb * 4];
        float yrv[4] = {yr.x, yr.y, yr.z, yr.w};
        float yiv[4] = {yi.x, yi.y, yi.z, yi.w};
#pragma unroll
        for (int j = 0; j < 4; j++) {
            float zr = bf2f((unsigned short)zrh[j]) + bf2f((unsigned short)zrl[j]);
            float zi = bf2f((unsigned short)zih[j]) + bf2f((unsigned short)zil[j]);
            sre += yrv[j] * zr + yiv[j] * zi;
            sim += yiv[j] * zr - yrv[j] * zi;
        }
    }
    Sp[((size_t)gz * 4 + b) * FHP + f] = make_float2(sre, sim);
}

// ---------------- inverse FFT (sums 8 partials) -> ac_mean ----------------
__global__ __launch_bounds__(512) void ifft_kernel(const float2* __restrict__ Sp,
                                                   float* __restrict__ acm)
{
    __shared__ float lre[4608];
    __shared__ float lim[4608];
    const int b = blockIdx.x, tid = threadIdx.x;
    float xr[8], xi[8];
#pragma unroll
    for (int s = 0; s < 8; s++) {
        int idx = tid + 512 * s;
        int src = (idx <= 2048) ? idx : (4096 - idx);
        float sx = 0.f, sy = 0.f;
#pragma unroll
        for (int gz = 0; gz < 8; gz++) {
            float2 v = Sp[((size_t)gz * 4 + b) * FHP + src];
            sx += v.x; sy += v.y;
        }
        xr[s] = sx;
        xi[s] = (idx <= 2048) ? sy : -sy;
    }
    fft_core<1>(xr, xi, lre, lim, tid);
    const float scale = 1.0f / ((float)T_ * (float)E_);
#pragma unroll
    for (int s = 0; s < 8; s++) {
        int p = tid + 512 * s;
        acm[b * T_ + p] = lre[SW(p)] * scale;
    }
}

// ---------------- top-k (24) + softmax, per batch ----------------
__global__ __launch_bounds__(256) void topk_kernel(const float* __restrict__ acm,
                                                   int* __restrict__ delays,
                                                   float* __restrict__ weights)
{
    __shared__ float vals[4096];
    __shared__ float bv[256];
    __shared__ int   bi[256];
    __shared__ float topv[TOPK];
    const int b = blockIdx.x, tid = threadIdx.x;
#pragma unroll
    for (int s = 0; s < 16; s++) vals[tid + 256 * s] = acm[b * T_ + tid + 256 * s];
    __syncthreads();
    for (int it = 0; it < TOPK; it++) {
        float best = -INFINITY; int bidx = 0;
#pragma unroll
        for (int s = 0; s < 16; s++) {
            int idx = tid * 16 + s;
            float v = vals[idx];
            if (v > best) { best = v; bidx = idx; }
        }
        bv[tid] = best; bi[tid] = bidx;
        __syncthreads();
        for (int off = 128; off > 0; off >>= 1) {
            if (tid < off) {
                if (bv[tid + off] > bv[tid] ||
                    (bv[tid + off] == bv[tid] && bi[tid + off] < bi[tid])) {
                    bv[tid] = bv[tid + off]; bi[tid] = bi[tid + off];
                }
            }
            __syncthreads();
        }
        if (tid == 0) {
            delays[b * TOPK + it] = bi[0];
            topv[it] = bv[0];
            vals[bi[0]] = -INFINITY;
        }
        __syncthreads();
    }
    if (tid == 0) {
        float mx = topv[0];
        float w[TOPK], sum = 0.f;
        for (int i = 0; i < TOPK; i++) { w[i] = expf(topv[i] - mx); sum += w[i]; }
        for (int i = 0; i < TOPK; i++) weights[b * TOPK + i] = w[i] / sum;
    }
}

// ---------------- agg: weighted circular gather of bf16 V ----------------
__global__ __launch_bounds__(256) void agg_kernel(const unsigned short* __restrict__ V,
                                                  const int* __restrict__ delays,
                                                  const float* __restrict__ wts,
                                                  unsigned short* __restrict__ agg)
{
    __shared__ int   dly[B_][TOPK];
    __shared__ float wt[B_][TOPK];
    const int tid = threadIdx.x, b = blockIdx.y;
    if (tid < B_ * TOPK) {
        dly[tid / TOPK][tid % TOPK] = delays[tid];
        wt[tid / TOPK][tid % TOPK]  = wts[tid];
    }
    __syncthreads();
    const int lane = tid & 63, w = tid >> 6;
    const int t = blockIdx.x * 4 + w;
    const int e8 = lane * 8;
    const int h = e8 >> 6;
    const int c = (b * H_ + h) % B_;
    const unsigned short* Vb = V + (size_t)b * T_ * E_;
    float acc[8];
#pragma unroll
    for (int j = 0; j < 8; j++) acc[j] = 0.f;
#pragma unroll
    for (int i = 0; i < TOPK; i++) {
        int tt = (t + dly[c][i]) & (T_ - 1);
        bf16x8 v = *(const bf16x8*)&Vb[(size_t)tt * E_ + e8];
        float wg = wt[c][i];
#pragma unroll
        for (int j = 0; j < 8; j++)
            acc[j] += wg * bf2f((unsigned short)v[j]);
    }
    bf16x8 o;
#pragma unroll
    for (int j = 0; j < 8; j++) o[j] = (short)f2bf(acc[j]);
    *(bf16x8*)&agg[((size_t)b * T_ + t) * E_ + e8] = o;
}

// ---------------- launch ----------------
extern "C" void kernel_launch(void* const* d_in, const int* in_sizes, int n_in,
                              void* d_out, int out_size, void* d_ws, size_t ws_size,
                              hipStream_t stream)
{
    const float* hidden = (const float*)d_in[0];
    const float* Wq = (const float*)d_in[1];
    const float* Wk = (const float*)d_in[3];
    const float* Wv = (const float*)d_in[5]; const float* bv = (const float*)d_in[6];
    const float* Wo = (const float*)d_in[7]; const float* bo = (const float*)d_in[8];

    char* ws = (char*)d_ws;
    const size_t YA_OFF  = 0;                  // 33.8 MB: Htr fp32, later Y fp32
    const size_t AH_OFF  = 33816576;           // 16.8 MB: Ah bf16, later Ag bf16
    const size_t ZH_OFF  = 50593792;           // 16.9 MB
    const size_t ZL_OFF  = 67502080;           // 16.9 MB
    const size_t VB_OFF  = 84410368;           // 16.8 MB: Mp partials, then Vb bf16
    const size_t MTH_OFF = 101187584;          // 512 KB
    const size_t MTL_OFF = 101711872;          // 512 KB
    const size_t WVH_OFF = 102236160;          // 512 KB
    const size_t WOH_OFF = 102760448;          // 512 KB
    const size_t SP_OFF  = 103284736;          // 528 KB (8 partials x 4 x FHP float2)
    const size_t ACM_OFF = 103813120;          // 64 KB
    const size_t DEL_OFF = 103878656;          // 384 B
    const size_t WTS_OFF = 103879040;          // 384 B
    if (ws_size < 103879424) return;

    float* Htr = (float*)(ws + YA_OFF);
    float* Y   = (float*)(ws + YA_OFF);
    unsigned short* Ah  = (unsigned short*)(ws + AH_OFF);
    unsigned short* Ag  = (unsigned short*)(ws + AH_OFF);
    unsigned short* Zh  = (unsigned short*)(ws + ZH_OFF);
    unsigned short* Zl  = (unsigned short*)(ws + ZL_OFF);
    float* Mp           = (float*)(ws + VB_OFF);
    unsigned short* Vb  = (unsigned short*)(ws + VB_OFF);
    unsigned short* Mth = (unsigned short*)(ws + MTH_OFF);
    unsigned short* Mtl = (unsigned short*)(ws + MTL_OFF);
    unsigned short* Wvh = (unsigned short*)(ws + WVH_OFF);
    unsigned short* Woh = (unsigned short*)(ws + WOH_OFF);
    float2* Sp   = (float2*)(ws + SP_OFF);
    float*  acm  = (float*)(ws + ACM_OFF);
    int*    delays = (int*)(ws + DEL_OFF);
    float*  wts    = (float*)(ws + WTS_OFF);

    // prep: transpose+split hidden; split Wv/Wo; M = Wq^T Wk via split-K partials
    dim3 tg(64, 8, 4);
    trsp_split<<<tg, 256, 0, stream>>>(hidden, Htr, Ah);
    dim3 swg(256, 2);
    split_w2<<<swg, 256, 0, stream>>>(Wv, Wo, Wvh, Woh);
    dim3 mg(4, 4, 16);
    wprep_partial<<<mg, 256, 0, stream>>>(Wq, Wk, Mp);
    reduce_split_m<<<256, 256, 0, stream>>>(Mp, Mth, Mtl);

    // V GEMM (bf16 out) — overwrites Mp region (dead after reduce)
    dim3 gv(8, 128);
    mfma_gemm<1, 0, 2, 1><<<gv, 256, 0, stream>>>(Ah, Ah, Wvh, Wvh, bv, Vb);

    // FFT of hidden -> split Z — frees Htr afterwards
    fft_fwd_z<<<512, 512, 0, stream>>>(Htr, Zh, Zl);

    // Y = Z * M^T (3-pass split), fp32 out into Htr-space
    dim3 gy(8, 129);
    mfma_gemm<3, 1, 0, 0><<<gy, 256, 0, stream>>>(Zh, Zl, Mth, Mtl, bv, Y);

    // Sp[gz][b][f] = partial row-dot(Y, conj(Z))
    dim3 dg(9, 4, 8);
    dot_s<<<dg, 256, 0, stream>>>(Y, Zh, Zl, Sp);

    // ac_mean (sums partials), top-k, weighted gather, output projection
    ifft_kernel<<<B_, 512, 0, stream>>>(Sp, acm);
    topk_kernel<<<B_, 256, 0, stream>>>(acm, delays, wts);
    dim3 ag(T_ / 4, B_);
    agg_kernel<<<ag, 256, 0, stream>>>(Vb, delays, wts, Ag);
    mfma_gemm<1, 0, 0, 1><<<gv, 256, 0, stream>>>(Ag, Ag, Woh, Woh, bo, (float*)d_out);
}

// Round 8
// 251.882 us; speedup vs baseline: 1.3615x; 1.1330x over previous
//
#include <hip/hip_runtime.h>
#include <math.h>

#define B_ 4
#define T_ 4096
#define E_ 512
#define H_ 8
#define TOPK 24
#define FH 2049
#define FHP 2064
#define F2 2064
#define ZROWS 16512   // B * 2 * F2  (plane-major: row = (b*2+plane)*F2 + f)
#define NRH 16384     // B * T  (hidden / agg rows)

typedef __attribute__((ext_vector_type(8))) short bf16x8;
typedef __attribute__((ext_vector_type(4))) float f32x4;

__device__ __forceinline__ unsigned short f2bf(float f) {
    unsigned u = __float_as_uint(f);
    u = (u + 0x7FFFu + ((u >> 16) & 1u)) >> 16;
    return (unsigned short)u;
}
__device__ __forceinline__ float bf2f(unsigned short h) {
    return __uint_as_float(((unsigned)h) << 16);
}
__device__ __forceinline__ void glds16(const unsigned short* g, short* l) {
    __builtin_amdgcn_global_load_lds(
        (const __attribute__((address_space(1))) unsigned int*)g,
        (__attribute__((address_space(3))) unsigned int*)l, 16, 0, 0);
}

// kc8 layout helper: element (row, k) of a [NR x 512] bf16 matrix lives at
//   ((k>>3)*NR + row)*8 + (k&7)

// ------- transpose hidden [B,T,E]->[B,E,T] fp32 + bf16 (hi) kc8 -------
__global__ __launch_bounds__(256) void trsp_split(const float* __restrict__ hid,
                                                  float* __restrict__ Htr,
                                                  unsigned short* __restrict__ Ah)
{
    __shared__ float tile[64][68];
    const int b = blockIdx.z;
    const int t0 = blockIdx.x * 64, e0 = blockIdx.y * 64;
    const int r = threadIdx.x >> 4;
    const int c4 = (threadIdx.x & 15) * 4;
#pragma unroll
    for (int s = 0; s < 4; s++) {
        int t = t0 + r + 16 * s;
        float4 v = *(const float4*)&hid[((size_t)b * T_ + t) * E_ + e0 + c4];
        tile[r + 16 * s][c4 + 0] = v.x; tile[r + 16 * s][c4 + 1] = v.y;
        tile[r + 16 * s][c4 + 2] = v.z; tile[r + 16 * s][c4 + 3] = v.w;
        ushort4 hv = make_ushort4(f2bf(v.x), f2bf(v.y), f2bf(v.z), f2bf(v.w));
        int e = e0 + c4;
        int rowg = b * T_ + t;
        *(ushort4*)&Ah[((size_t)(e >> 3) * NRH + rowg) * 8 + (e & 7)] = hv;
    }
    __syncthreads();
#pragma unroll
    for (int s = 0; s < 4; s++) {
        int e = e0 + r + 16 * s;
        float4 o;
        o.x = tile[c4 + 0][r + 16 * s];
        o.y = tile[c4 + 1][r + 16 * s];
        o.z = tile[c4 + 2][r + 16 * s];
        o.w = tile[c4 + 3][r + 16 * s];
        *(float4*)&Htr[((size_t)b * E_ + e) * T_ + t0 + c4] = o;
    }
}

// ------- split Wv, Wo to bf16 hi, kc8 layout (rows = m, 512) -------
__global__ __launch_bounds__(256) void split_w2(const float* __restrict__ wv,
                                                const float* __restrict__ wo,
                                                unsigned short* __restrict__ Wvh,
                                                unsigned short* __restrict__ Woh)
{
    const float* src = blockIdx.y ? wo : wv;
    unsigned short* dst = blockIdx.y ? Woh : Wvh;
    int i = (blockIdx.x * 256 + threadIdx.x) * 4;
    int m = i >> 9, k = i & 511;
    float4 v = *(const float4*)&src[i];
    *(ushort4*)&dst[((size_t)(k >> 3) * 512 + m) * 8 + (k & 7)] =
        make_ushort4(f2bf(v.x), f2bf(v.y), f2bf(v.z), f2bf(v.w));
}

// ------- M^T partials: Mp[z][j][k] = sum_{e in chunk z} Wq[e,k]*Wk[e,j] -------
__global__ __launch_bounds__(256) void wprep_partial(const float* __restrict__ Wq,
                                                     const float* __restrict__ Wk,
                                                     float* __restrict__ Mp)
{
    __shared__ float As[8][132];
    __shared__ float Bs[8][132];
    const int j0 = blockIdx.x * 128, k0 = blockIdx.y * 128;
    const int e0 = blockIdx.z * 32;
    const int tid = threadIdx.x;
    const int tm = tid & 15, tn = tid >> 4;
    const int le = tid >> 5, lc = (tid & 31) * 4;
    float acc[8][8];
#pragma unroll
    for (int i = 0; i < 8; i++)
#pragma unroll
        for (int j = 0; j < 8; j++) acc[i][j] = 0.f;
    for (int eb = e0; eb < e0 + 32; eb += 8) {
        __syncthreads();
        *(float4*)&As[le][lc] = *(const float4*)&Wq[((size_t)(eb + le)) * 512 + k0 + lc];
        *(float4*)&Bs[le][lc] = *(const float4*)&Wk[((size_t)(eb + le)) * 512 + j0 + lc];
        __syncthreads();
#pragma unroll
        for (int e = 0; e < 8; e++) {
            float a[8], bb[8];
            *(float4*)&a[0] = *(float4*)&As[e][4 * tn];
            *(float4*)&a[4] = *(float4*)&As[e][64 + 4 * tn];
            *(float4*)&bb[0] = *(float4*)&Bs[e][4 * tm];
            *(float4*)&bb[4] = *(float4*)&Bs[e][64 + 4 * tm];
#pragma unroll
            for (int i = 0; i < 8; i++)
#pragma unroll
                for (int j = 0; j < 8; j++)
                    acc[i][j] += a[i] * bb[j];
        }
    }
    float* out = Mp + (size_t)blockIdx.z * 512 * 512;
#pragma unroll
    for (int jj = 0; jj < 8; jj++) {
        int j = j0 + ((jj < 4) ? (4 * tm + jj) : (64 + 4 * tm + jj - 4));
        float4 o0 = make_float4(acc[0][jj], acc[1][jj], acc[2][jj], acc[3][jj]);
        float4 o1 = make_float4(acc[4][jj], acc[5][jj], acc[6][jj], acc[7][jj]);
        *(float4*)&out[(size_t)j * 512 + k0 + 4 * tn] = o0;
        *(float4*)&out[(size_t)j * 512 + k0 + 64 + 4 * tn] = o1;
    }
}

// ------- reduce 16 partials, split to bf16 hi/lo, kc8 layout -------
__global__ __launch_bounds__(256) void reduce_split_m(const float* __restrict__ Mp,
                                                      unsigned short* __restrict__ Mth,
                                                      unsigned short* __restrict__ Mtl)
{
    int i = (blockIdx.x * 256 + threadIdx.x) * 4;
    if (i >= 512 * 512) return;
    float4 s = make_float4(0.f, 0.f, 0.f, 0.f);
#pragma unroll
    for (int z = 0; z < 16; z++) {
        float4 v = *(const float4*)&Mp[(size_t)z * 262144 + i];
        s.x += v.x; s.y += v.y; s.z += v.z; s.w += v.w;
    }
    int j = i >> 9, k = i & 511;
    float f[4] = {s.x, s.y, s.z, s.w};
    unsigned short hh[4], ll[4];
#pragma unroll
    for (int r = 0; r < 4; r++) {
        hh[r] = f2bf(f[r]);
        ll[r] = f2bf(f[r] - bf2f(hh[r]));
    }
    size_t o = ((size_t)(k >> 3) * 512 + j) * 8 + (k & 7);
    *(ushort4*)&Mth[o] = make_ushort4(hh[0], hh[1], hh[2], hh[3]);
    *(ushort4*)&Mtl[o] = make_ushort4(ll[0], ll[1], ll[2], ll[3]);
}

// ---------------- m97-style MFMA GEMM body: tile 128x128, BK=32 ----------------
// A,B in kc8 layout. OMODE: 0 = fp32 natural, 2 = bf16 natural. HASBIAS 0/1.
template<int PASSES, int OMODE, int HASBIAS>
__device__ __forceinline__ void gemm_body(const unsigned short* __restrict__ Ah,
                                          const unsigned short* __restrict__ Al, int nrA,
                                          const unsigned short* __restrict__ Bh,
                                          const unsigned short* __restrict__ Bl,
                                          const float* __restrict__ bias,
                                          void* __restrict__ Cp,
                                          int m0, int n0, short* smem)
{
    const int tid = threadIdx.x;
    const int wid = tid >> 6, lane = tid & 63;
    const int wn = wid >> 1, wm = wid & 1;
    const int lr = lane & 15, lg = lane >> 4;

    f32x4 acc[4][4];
#pragma unroll
    for (int i = 0; i < 4; i++)
#pragma unroll
        for (int j = 0; j < 4; j++) acc[i][j] = (f32x4)0.f;

    constexpr int SEGW = (PASSES == 3) ? 8 : 4;   // glds segments per wave per step

    for (int kc0 = 0; kc0 < 64; kc0 += 4) {
        __syncthreads();                            // LDS free (prev compute done)
#pragma unroll
        for (int s = 0; s < SEGW; s++) {
            const int sg = wid * SEGW + s;
            const int tile = sg >> 3;               // 0=Ah 1=Bh 2=Al 3=Bl (wave-uniform)
            const int seg = sg & 7;
            const int c = seg >> 1, h = seg & 1;
            const unsigned short* bp;
            size_t ro;
            if (tile == 0)      { bp = Ah; ro = (size_t)(kc0 + c) * (size_t)nrA + n0 + h * 64; }
            else if (tile == 1) { bp = Bh; ro = (size_t)(kc0 + c) * 512 + m0 + h * 64; }
            else if (tile == 2) { bp = Al; ro = (size_t)(kc0 + c) * (size_t)nrA + n0 + h * 64; }
            else                { bp = Bl; ro = (size_t)(kc0 + c) * 512 + m0 + h * 64; }
            glds16(bp + ro * 8 + (size_t)lane * 8, smem + tile * 4096 + seg * 512);
        }
        __syncthreads();                            // drains vmcnt(0): loads landed

        bf16x8 a[4], b[4];
#pragma unroll
        for (int f = 0; f < 4; f++) {
            a[f] = *(bf16x8*)&smem[       (lg * 128 + wn * 64 + f * 16 + lr) * 8];
            b[f] = *(bf16x8*)&smem[4096 + (lg * 128 + wm * 64 + f * 16 + lr) * 8];
        }
        if (PASSES == 3) {
            bf16x8 a2[4], b2[4];
#pragma unroll
            for (int f = 0; f < 4; f++) {
                a2[f] = *(bf16x8*)&smem[8192  + (lg * 128 + wn * 64 + f * 16 + lr) * 8];
                b2[f] = *(bf16x8*)&smem[12288 + (lg * 128 + wm * 64 + f * 16 + lr) * 8];
            }
#pragma unroll
            for (int i = 0; i < 4; i++)
#pragma unroll
                for (int j = 0; j < 4; j++) {
                    acc[i][j] = __builtin_amdgcn_mfma_f32_16x16x32_bf16(a[i], b[j], acc[i][j], 0, 0, 0);
                    acc[i][j] = __builtin_amdgcn_mfma_f32_16x16x32_bf16(a[i], b2[j], acc[i][j], 0, 0, 0);
                    acc[i][j] = __builtin_amdgcn_mfma_f32_16x16x32_bf16(a2[i], b[j], acc[i][j], 0, 0, 0);
                }
        } else {
#pragma unroll
            for (int i = 0; i < 4; i++)
#pragma unroll
                for (int j = 0; j < 4; j++)
                    acc[i][j] = __builtin_amdgcn_mfma_f32_16x16x32_bf16(a[i], b[j], acc[i][j], 0, 0, 0);
        }
    }

    float bs[4];
#pragma unroll
    for (int j = 0; j < 4; j++) bs[j] = HASBIAS ? bias[m0 + wm * 64 + j * 16 + lr] : 0.f;

    if (OMODE == 0) {
        float* C = (float*)Cp;
#pragma unroll
        for (int i = 0; i < 4; i++)
#pragma unroll
            for (int j = 0; j < 4; j++) {
                int m = m0 + wm * 64 + j * 16 + lr;
#pragma unroll
                for (int r = 0; r < 4; r++) {
                    int n = n0 + wn * 64 + i * 16 + lg * 4 + r;
                    C[(size_t)n * 512 + m] = acc[i][j][r] + bs[j];
                }
            }
    } else {
        unsigned short* C = (unsigned short*)Cp;
#pragma unroll
        for (int i = 0; i < 4; i++)
#pragma unroll
            for (int j = 0; j < 4; j++) {
                int m = m0 + wm * 64 + j * 16 + lr;
#pragma unroll
                for (int r = 0; r < 4; r++) {
                    int n = n0 + wn * 64 + i * 16 + lg * 4 + r;
                    C[(size_t)n * 512 + m] = f2bf(acc[i][j][r] + bs[j]);
                }
            }
    }
}

// fused dispatch: z=0 -> V GEMM (1-pass, bf16 natural out), z=1 -> Y GEMM (3-pass, fp32)
__global__ __launch_bounds__(256) void fused_vy(const unsigned short* __restrict__ Ah,
                                                const unsigned short* __restrict__ Wvh,
                                                const float* __restrict__ bv,
                                                unsigned short* __restrict__ Vb,
                                                const unsigned short* __restrict__ Zh,
                                                const unsigned short* __restrict__ Zl,
                                                const unsigned short* __restrict__ Mth,
                                                const unsigned short* __restrict__ Mtl,
                                                float* __restrict__ Y)
{
    __shared__ short smem[16384];
    const int m0 = blockIdx.x * 128;
    const int n0 = blockIdx.y * 128;
    if (blockIdx.z == 0) {
        if (blockIdx.y >= 128) return;
        gemm_body<1, 2, 1>(Ah, Ah, NRH, Wvh, Wvh, bv, Vb, m0, n0, smem);
    } else {
        gemm_body<3, 0, 0>(Zh, Zl, ZROWS, Mth, Mtl, nullptr, Y, m0, n0, smem);
    }
}

__global__ __launch_bounds__(256) void o_gemm(const unsigned short* __restrict__ Ag,
                                              const unsigned short* __restrict__ Woh,
                                              const float* __restrict__ bo,
                                              float* __restrict__ C)
{
    __shared__ short smem[8192];
    gemm_body<1, 0, 1>(Ag, Ag, NRH, Woh, Woh, bo, C, blockIdx.x * 128, blockIdx.y * 128, smem);
}

// ================= radix-8 register FFT (N = 4096 = 8^4) =================
template<int SGN>
__device__ __forceinline__ void radix8(float* xr, float* xi)
{
    const float C = 0.70710678118654752440f;
    const float S = (float)SGN;
    float t0r = xr[0] + xr[4], t0i = xi[0] + xi[4];
    float t1r = xr[1] + xr[5], t1i = xi[1] + xi[5];
    float t2r = xr[2] + xr[6], t2i = xi[2] + xi[6];
    float t3r = xr[3] + xr[7], t3i = xi[3] + xi[7];
    float u0r = xr[0] - xr[4], u0i = xi[0] - xi[4];
    float a1r = xr[1] - xr[5], a1i = xi[1] - xi[5];
    float a2r = xr[2] - xr[6], a2i = xi[2] - xi[6];
    float a3r = xr[3] - xr[7], a3i = xi[3] - xi[7];
    float u1r = C * (a1r - S * a1i), u1i = C * (S * a1r + a1i);
    float u2r = -S * a2i,             u2i = S * a2r;
    float u3r = -C * (a3r + S * a3i), u3i = C * (S * a3r - a3i);
    float v0r = t0r + t2r, v0i = t0i + t2i;
    float w0r = t0r - t2r, w0i = t0i - t2i;
    float v1r = t1r + t3r, v1i = t1i + t3i;
    float w1r = -S * (t1i - t3i), w1i = S * (t1r - t3r);
    float p0r = u0r + u2r, p0i = u0i + u2i;
    float q0r = u0r - u2r, q0i = u0i - u2i;
    float p1r = u1r + u3r, p1i = u1i + u3i;
    float q1r = -S * (u1i - u3i), q1i = S * (u1r - u3r);
    xr[0] = v0r + v1r; xi[0] = v0i + v1i;
    xr[4] = v0r - v1r; xi[4] = v0i - v1i;
    xr[2] = w0r + w1r; xi[2] = w0i + w1i;
    xr[6] = w0r - w1r; xi[6] = w0i - w1i;
    xr[1] = p0r + p1r; xi[1] = p0i + p1i;
    xr[5] = p0r - p1r; xi[5] = p0i - p1i;
    xr[3] = q0r + q1r; xi[3] = q0i + q1i;
    xr[7] = q0r - q1r; xi[7] = q0i - q1i;
}

__device__ __forceinline__ void twmul(float& xr, float& xi, float wc, float ws)
{
    float a = xr, b = xi;
    xr = a * wc - b * ws;
    xi = a * ws + b * wc;
}

__device__ __forceinline__ void twiddle7(float* xr, float* xi, int n, float ang)
{
    float s1, c1;
    __sincosf(ang * (float)n, &s1, &c1);
    float wc = c1, ws = s1;
    twmul(xr[1], xi[1], wc, ws);
#pragma unroll
    for (int r = 2; r < 8; r++) {
        float nc = wc * c1 - ws * s1;
        float ns = wc * s1 + ws * c1;
        wc = nc; ws = ns;
        twmul(xr[r], xi[r], wc, ws);
    }
}

#define SW(i) ((i) + ((i) >> 3))

template<int SGN>
__device__ __forceinline__ void fft_core(float* xr, float* xi,
                                         float* lre, float* lim, int tid)
{
    const float TW = (float)SGN * 6.28318530717958647693f;
    __syncthreads();
    radix8<SGN>(xr, xi);
    twiddle7(xr, xi, tid, TW / 4096.f);
#pragma unroll
    for (int r = 0; r < 8; r++) {
        int idx = r * 512 + tid;
        lre[SW(idx)] = xr[r]; lim[SW(idx)] = xi[r];
    }
    __syncthreads();
    const int b2 = (tid >> 6) * 512, n2 = tid & 63;
#pragma unroll
    for (int s = 0; s < 8; s++) {
        int idx = b2 + n2 + s * 64;
        xr[s] = lre[SW(idx)]; xi[s] = lim[SW(idx)];
    }
    __syncthreads();
    radix8<SGN>(xr, xi);
    twiddle7(xr, xi, n2, TW / 512.f);
#pragma unroll
    for (int r = 0; r < 8; r++) {
        int idx = b2 + r * 64 + n2;
        lre[SW(idx)] = xr[r]; lim[SW(idx)] = xi[r];
    }
    __syncthreads();
    const int b3 = (tid >> 3) * 64, n3 = tid & 7;
#pragma unroll
    for (int s = 0; s < 8; s++) {
        int idx = b3 + n3 + s * 8;
        xr[s] = lre[SW(idx)]; xi[s] = lim[SW(idx)];
    }
    __syncthreads();
    radix8<SGN>(xr, xi);
    twiddle7(xr, xi, n3, TW / 64.f);
#pragma unroll
    for (int r = 0; r < 8; r++) {
        int idx = b3 + r * 8 + n3;
        lre[SW(idx)] = xr[r]; lim[SW(idx)] = xi[r];
    }
    __syncthreads();
#pragma unroll
    for (int s = 0; s < 8; s++) {
        int idx = tid * 8 + s;
        xr[s] = lre[SW(idx)]; xi[s] = lim[SW(idx)];
    }
    __syncthreads();
    radix8<SGN>(xr, xi);
    const int fr = ((tid & 7) << 6) | (((tid >> 3) & 7) << 3) | (tid >> 6);
#pragma unroll
    for (int r = 0; r < 8; r++) {
        int f = r * 512 + fr;
        lre[SW(f)] = xr[r]; lim[SW(f)] = xi[r];
    }
    __syncthreads();
}

// ------- forward FFT of hidden: 2 packed FFTs (4 channels)/block, kc8 Z out -------
__global__ __launch_bounds__(512) void fft_fwd_z(const float* __restrict__ Htr,
                                                 unsigned short* __restrict__ Zh,
                                                 unsigned short* __restrict__ Zl)
{
    __shared__ float lre[4608];
    __shared__ float lim[4608];
    const int bid = blockIdx.x;          // 0..511
    const int tid = threadIdx.x;
    const int b = bid >> 7;
    const int e0 = (bid & 127) * 4;
    unsigned uh[4][2][2], ul[4][2][2];   // [s][plane][p]
#pragma unroll
    for (int p = 0; p < 2; p++) {
        const float* he = Htr + ((size_t)(b * 512 + e0 + 2 * p)) * 4096;
        const float* ho = Htr + ((size_t)(b * 512 + e0 + 2 * p + 1)) * 4096;
        float xr[8], xi[8];
#pragma unroll
        for (int s = 0; s < 8; s++) {
            xr[s] = he[tid + 512 * s];
            xi[s] = ho[tid + 512 * s];
        }
        fft_core<-1>(xr, xi, lre, lim, tid);
#pragma unroll
        for (int s = 0; s < 4; s++) {
            int f = tid + 512 * s;
            int nf = (4096 - f) & 4095;
            float Ax = lre[SW(f)],  Ay = lim[SW(f)];
            float Bx = lre[SW(nf)], By = lim[SW(nf)];
            float qx = 0.5f * (Ax + Bx), qy = 0.5f * (Ay - By);
            float kx = 0.5f * (Ay + By), ky = -0.5f * (Ax - Bx);
            unsigned short h0 = f2bf(qx), h1 = f2bf(kx);
            uh[s][0][p] = (unsigned)h0 | ((unsigned)h1 << 16);
            ul[s][0][p] = (unsigned)f2bf(qx - bf2f(h0)) | ((unsigned)f2bf(kx - bf2f(h1)) << 16);
            unsigned short h2 = f2bf(qy), h3 = f2bf(ky);
            uh[s][1][p] = (unsigned)h2 | ((unsigned)h3 << 16);
            ul[s][1][p] = (unsigned)f2bf(qy - bf2f(h2)) | ((unsigned)f2bf(ky - bf2f(h3)) << 16);
        }
        if (tid == 0) {
            float vals[2] = {lre[SW(2048)], lim[SW(2048)]};
            size_t row0 = (size_t)(b * 2) * F2 + 2048;
#pragma unroll
            for (int q = 0; q < 2; q++) {
                int e = e0 + 2 * p + q;
                size_t o0 = ((size_t)(e >> 3) * ZROWS + row0) * 8 + (e & 7);
                unsigned short h = f2bf(vals[q]);
                Zh[o0] = h; Zl[o0] = f2bf(vals[q] - bf2f(h));
                size_t o1 = ((size_t)(e >> 3) * ZROWS + row0 + F2) * 8 + (e & 7);
                Zh[o1] = 0; Zl[o1] = 0;
            }
        }
    }
#pragma unroll
    for (int s = 0; s < 4; s++)
#pragma unroll
        for (int c = 0; c < 2; c++) {
            size_t row = (size_t)(b * 2 + c) * F2 + tid + 512 * s;
            size_t off = ((size_t)(e0 >> 3) * ZROWS + row) * 8 + (e0 & 7);
            ushort4 vh = make_ushort4((unsigned short)(uh[s][c][0] & 0xffff),
                                      (unsigned short)(uh[s][c][0] >> 16),
                                      (unsigned short)(uh[s][c][1] & 0xffff),
                                      (unsigned short)(uh[s][c][1] >> 16));
            ushort4 vl = make_ushort4((unsigned short)(ul[s][c][0] & 0xffff),
                                      (unsigned short)(ul[s][c][0] >> 16),
                                      (unsigned short)(ul[s][c][1] & 0xffff),
                                      (unsigned short)(ul[s][c][1] >> 16));
            *(ushort4*)&Zh[off] = vh;
            *(ushort4*)&Zl[off] = vl;
        }
}

// ------- Sp[gz][b][f] = partial sum over e-chunks of Y[row,e] * conj(z[e]) -------
__global__ __launch_bounds__(256) void dot_s(const float* __restrict__ Y,
                                             const unsigned short* __restrict__ Zh,
                                             const unsigned short* __restrict__ Zl,
                                             float2* __restrict__ Sp)
{
    const int f = blockIdx.x * 256 + threadIdx.x;
    const int b = blockIdx.y;
    const int gz = blockIdx.z;
    if (f > 2048) return;
    const size_t row_re = (size_t)(b * 2) * F2 + f;
    const size_t row_im = row_re + F2;
    float sre = 0.f, sim = 0.f;
    for (int c = gz * 8; c < gz * 8 + 8; c++) {
        bf16x8 zrh = *(const bf16x8*)&Zh[((size_t)c * ZROWS + row_re) * 8];
        bf16x8 zrl = *(const bf16x8*)&Zl[((size_t)c * ZROWS + row_re) * 8];
        bf16x8 zih = *(const bf16x8*)&Zh[((size_t)c * ZROWS + row_im) * 8];
        bf16x8 zil = *(const bf16x8*)&Zl[((size_t)c * ZROWS + row_im) * 8];
        float4 yr0 = *(const float4*)&Y[row_re * 512 + c * 8];
        float4 yr1 = *(const float4*)&Y[row_re * 512 + c * 8 + 4];
        float4 yi0 = *(const float4*)&Y[row_im * 512 + c * 8];
        float4 yi1 = *(const float4*)&Y[row_im * 512 + c * 8 + 4];
        float yrv[8] = {yr0.x, yr0.y, yr0.z, yr0.w, yr1.x, yr1.y, yr1.z, yr1.w};
        float yiv[8] = {yi0.x, yi0.y, yi0.z, yi0.w, yi1.x, yi1.y, yi1.z, yi1.w};
#pragma unroll
        for (int j = 0; j < 8; j++) {
            float zr = bf2f((unsigned short)zrh[j]) + bf2f((unsigned short)zrl[j]);
            float zi = bf2f((unsigned short)zih[j]) + bf2f((unsigned short)zil[j]);
            sre += yrv[j] * zr + yiv[j] * zi;
            sim += yiv[j] * zr - yrv[j] * zi;
        }
    }
    Sp[((size_t)gz * 4 + b) * FHP + f] = make_float2(sre, sim);
}

// ---------------- inverse FFT (sums 8 partials) -> ac_mean ----------------
__global__ __launch_bounds__(512) void ifft_kernel(const float2* __restrict__ Sp,
                                                   float* __restrict__ acm)
{
    __shared__ float lre[4608];
    __shared__ float lim[4608];
    const int b = blockIdx.x, tid = threadIdx.x;
    float xr[8], xi[8];
#pragma unroll
    for (int s = 0; s < 8; s++) {
        int idx = tid + 512 * s;
        int src = (idx <= 2048) ? idx : (4096 - idx);
        float sx = 0.f, sy = 0.f;
#pragma unroll
        for (int gz = 0; gz < 8; gz++) {
            float2 v = Sp[((size_t)gz * 4 + b) * FHP + src];
            sx += v.x; sy += v.y;
        }
        xr[s] = sx;
        xi[s] = (idx <= 2048) ? sy : -sy;
    }
    fft_core<1>(xr, xi, lre, lim, tid);
    const float scale = 1.0f / ((float)T_ * (float)E_);
#pragma unroll
    for (int s = 0; s < 8; s++) {
        int p = tid + 512 * s;
        acm[b * T_ + p] = lre[SW(p)] * scale;
    }
}

// ---------------- top-k (24) + softmax, per batch ----------------
__global__ __launch_bounds__(256) void topk_kernel(const float* __restrict__ acm,
                                                   int* __restrict__ delays,
                                                   float* __restrict__ weights)
{
    __shared__ float vals[4096];
    __shared__ float bv[256];
    __shared__ int   bi[256];
    __shared__ float topv[TOPK];
    const int b = blockIdx.x, tid = threadIdx.x;
#pragma unroll
    for (int s = 0; s < 16; s++) vals[tid + 256 * s] = acm[b * T_ + tid + 256 * s];
    __syncthreads();
    for (int it = 0; it < TOPK; it++) {
        float best = -INFINITY; int bidx = 0;
#pragma unroll
        for (int s = 0; s < 16; s++) {
            int idx = tid * 16 + s;
            float v = vals[idx];
            if (v > best) { best = v; bidx = idx; }
        }
        bv[tid] = best; bi[tid] = bidx;
        __syncthreads();
        for (int off = 128; off > 0; off >>= 1) {
            if (tid < off) {
                if (bv[tid + off] > bv[tid] ||
                    (bv[tid + off] == bv[tid] && bi[tid + off] < bi[tid])) {
                    bv[tid] = bv[tid + off]; bi[tid] = bi[tid + off];
                }
            }
            __syncthreads();
        }
        if (tid == 0) {
            delays[b * TOPK + it] = bi[0];
            topv[it] = bv[0];
            vals[bi[0]] = -INFINITY;
        }
        __syncthreads();
    }
    if (tid == 0) {
        float mx = topv[0];
        float w[TOPK], sum = 0.f;
        for (int i = 0; i < TOPK; i++) { w[i] = expf(topv[i] - mx); sum += w[i]; }
        for (int i = 0; i < TOPK; i++) weights[b * TOPK + i] = w[i] / sum;
    }
}

// ---------------- agg: weighted circular gather of bf16 V -> kc8 out ----------------
__global__ __launch_bounds__(256) void agg_kernel(const unsigned short* __restrict__ V,
                                                  const int* __restrict__ delays,
                                                  const float* __restrict__ wts,
                                                  unsigned short* __restrict__ agg)
{
    __shared__ int   dly[B_][TOPK];
    __shared__ float wt[B_][TOPK];
    const int tid = threadIdx.x, b = blockIdx.y;
    if (tid < B_ * TOPK) {
        dly[tid / TOPK][tid % TOPK] = delays[tid];
        wt[tid / TOPK][tid % TOPK]  = wts[tid];
    }
    __syncthreads();
    const int lane = tid & 63, w = tid >> 6;
    const int t = blockIdx.x * 4 + w;
    const int e8 = lane * 8;
    const int h = e8 >> 6;
    const int c = (b * H_ + h) % B_;
    const unsigned short* Vb = V + (size_t)b * T_ * E_;
    float acc[8];
#pragma unroll
    for (int j = 0; j < 8; j++) acc[j] = 0.f;
#pragma unroll
    for (int i = 0; i < TOPK; i++) {
        int tt = (t + dly[c][i]) & (T_ - 1);
        bf16x8 v = *(const bf16x8*)&Vb[(size_t)tt * E_ + e8];
        float wg = wt[c][i];
#pragma unroll
        for (int j = 0; j < 8; j++)
            acc[j] += wg * bf2f((unsigned short)v[j]);
    }
    bf16x8 o;
#pragma unroll
    for (int j = 0; j < 8; j++) o[j] = (short)f2bf(acc[j]);
    int rowg = b * T_ + t;
    *(bf16x8*)&agg[((size_t)(e8 >> 3) * NRH + rowg) * 8] = o;
}

// ---------------- launch ----------------
extern "C" void kernel_launch(void* const* d_in, const int* in_sizes, int n_in,
                              void* d_out, int out_size, void* d_ws, size_t ws_size,
                              hipStream_t stream)
{
    const float* hidden = (const float*)d_in[0];
    const float* Wq = (const float*)d_in[1];
    const float* Wk = (const float*)d_in[3];
    const float* Wv = (const float*)d_in[5]; const float* bv = (const float*)d_in[6];
    const float* Wo = (const float*)d_in[7]; const float* bo = (const float*)d_in[8];

    char* ws = (char*)d_ws;
    const size_t YA_OFF  = 0;                  // 33.8 MB: Htr fp32, later Y fp32
    const size_t AH_OFF  = 33816576;           // 16.8 MB: Ah bf16 kc8, later Ag kc8
    const size_t ZH_OFF  = 50593792;           // 16.9 MB
    const size_t ZL_OFF  = 67502080;           // 16.9 MB
    const size_t VB_OFF  = 84410368;           // 16.8 MB: Mp partials, then Vb bf16 natural
    const size_t MTH_OFF = 101187584;          // 512 KB
    const size_t MTL_OFF = 101711872;          // 512 KB
    const size_t WVH_OFF = 102236160;          // 512 KB
    const size_t WOH_OFF = 102760448;          // 512 KB
    const size_t SP_OFF  = 103284736;          // 528 KB
    const size_t ACM_OFF = 103813120;          // 64 KB
    const size_t DEL_OFF = 103878656;          // 384 B
    const size_t WTS_OFF = 103879040;          // 384 B
    if (ws_size < 103879424) return;

    float* Htr = (float*)(ws + YA_OFF);
    float* Y   = (float*)(ws + YA_OFF);
    unsigned short* Ah  = (unsigned short*)(ws + AH_OFF);
    unsigned short* Ag  = (unsigned short*)(ws + AH_OFF);
    unsigned short* Zh  = (unsigned short*)(ws + ZH_OFF);
    unsigned short* Zl  = (unsigned short*)(ws + ZL_OFF);
    float* Mp           = (float*)(ws + VB_OFF);
    unsigned short* Vb  = (unsigned short*)(ws + VB_OFF);
    unsigned short* Mth = (unsigned short*)(ws + MTH_OFF);
    unsigned short* Mtl = (unsigned short*)(ws + MTL_OFF);
    unsigned short* Wvh = (unsigned short*)(ws + WVH_OFF);
    unsigned short* Woh = (unsigned short*)(ws + WOH_OFF);
    float2* Sp   = (float2*)(ws + SP_OFF);
    float*  acm  = (float*)(ws + ACM_OFF);
    int*    delays = (int*)(ws + DEL_OFF);
    float*  wts    = (float*)(ws + WTS_OFF);

    // prep
    dim3 tg(64, 8, 4);
    trsp_split<<<tg, 256, 0, stream>>>(hidden, Htr, Ah);
    dim3 swg(256, 2);
    split_w2<<<swg, 256, 0, stream>>>(Wv, Wo, Wvh, Woh);
    dim3 mg(4, 4, 16);
    wprep_partial<<<mg, 256, 0, stream>>>(Wq, Wk, Mp);
    reduce_split_m<<<256, 256, 0, stream>>>(Mp, Mth, Mtl);

    // FFT of hidden -> split Z (kc8) — must precede fused V+Y
    fft_fwd_z<<<512, 512, 0, stream>>>(Htr, Zh, Zl);

    // fused: V GEMM (z=0, writes Vb over dead Mp) + Y GEMM (z=1, writes Y over dead Htr)
    dim3 gf(4, 129, 2);
    fused_vy<<<gf, 256, 0, stream>>>(Ah, Wvh, bv, Vb, Zh, Zl, Mth, Mtl, Y);

    // Sp = partial row-dot(Y, conj(Z))
    dim3 dg(9, 4, 8);
    dot_s<<<dg, 256, 0, stream>>>(Y, Zh, Zl, Sp);

    // ac_mean, top-k, gather, output projection
    ifft_kernel<<<B_, 512, 0, stream>>>(Sp, acm);
    topk_kernel<<<B_, 256, 0, stream>>>(acm, delays, wts);
    dim3 ag(T_ / 4, B_);
    agg_kernel<<<ag, 256, 0, stream>>>(Vb, delays, wts, Ag);
    dim3 go(4, 128);
    o_gemm<<<go, 256, 0, stream>>>(Ag, Woh, bo, (float*)d_out);
}

// Round 9
// 243.225 us; speedup vs baseline: 1.4099x; 1.0356x over previous
//
#include <hip/hip_runtime.h>
#include <math.h>

#define B_ 4
#define T_ 4096
#define E_ 512
#define H_ 8
#define TOPK 24
#define FH 2049
#define FHP 2064
#define F2 2064
#define ZROWS 16512   // B * 2 * F2  (plane-major: row = (b*2+plane)*F2 + f)
#define NRH 16384     // B * T  (hidden / agg rows)

typedef __attribute__((ext_vector_type(8))) short bf16x8;
typedef __attribute__((ext_vector_type(4))) float f32x4;

__device__ __forceinline__ unsigned short f2bf(float f) {
    unsigned u = __float_as_uint(f);
    u = (u + 0x7FFFu + ((u >> 16) & 1u)) >> 16;
    return (unsigned short)u;
}
__device__ __forceinline__ float bf2f(unsigned short h) {
    return __uint_as_float(((unsigned)h) << 16);
}
__device__ __forceinline__ void glds16(const unsigned short* g, short* l) {
    __builtin_amdgcn_global_load_lds(
        (const __attribute__((address_space(1))) unsigned int*)g,
        (__attribute__((address_space(3))) unsigned int*)l, 16, 0, 0);
}

// kc8 layout: element (row, k) of a [NR x 512] bf16 matrix lives at
//   ((k>>3)*NR + row)*8 + (k&7)

// ------- transpose hidden [B,T,E]->[B,E,T] fp32 + bf16 (hi) kc8 -------
__global__ __launch_bounds__(256) void trsp_split(const float* __restrict__ hid,
                                                  float* __restrict__ Htr,
                                                  unsigned short* __restrict__ Ah)
{
    __shared__ float tile[64][68];
    const int b = blockIdx.z;
    const int t0 = blockIdx.x * 64, e0 = blockIdx.y * 64;
    const int r = threadIdx.x >> 4;
    const int c4 = (threadIdx.x & 15) * 4;
#pragma unroll
    for (int s = 0; s < 4; s++) {
        int t = t0 + r + 16 * s;
        float4 v = *(const float4*)&hid[((size_t)b * T_ + t) * E_ + e0 + c4];
        tile[r + 16 * s][c4 + 0] = v.x; tile[r + 16 * s][c4 + 1] = v.y;
        tile[r + 16 * s][c4 + 2] = v.z; tile[r + 16 * s][c4 + 3] = v.w;
        ushort4 hv = make_ushort4(f2bf(v.x), f2bf(v.y), f2bf(v.z), f2bf(v.w));
        int e = e0 + c4;
        int rowg = b * T_ + t;
        *(ushort4*)&Ah[((size_t)(e >> 3) * NRH + rowg) * 8 + (e & 7)] = hv;
    }
    __syncthreads();
#pragma unroll
    for (int s = 0; s < 4; s++) {
        int e = e0 + r + 16 * s;
        float4 o;
        o.x = tile[c4 + 0][r + 16 * s];
        o.y = tile[c4 + 1][r + 16 * s];
        o.z = tile[c4 + 2][r + 16 * s];
        o.w = tile[c4 + 3][r + 16 * s];
        *(float4*)&Htr[((size_t)b * E_ + e) * T_ + t0 + c4] = o;
    }
}

// ------- split Wv, Wo to bf16 hi, kc8 layout -------
__global__ __launch_bounds__(256) void split_w2(const float* __restrict__ wv,
                                                const float* __restrict__ wo,
                                                unsigned short* __restrict__ Wvh,
                                                unsigned short* __restrict__ Woh)
{
    const float* src = blockIdx.y ? wo : wv;
    unsigned short* dst = blockIdx.y ? Woh : Wvh;
    int i = (blockIdx.x * 256 + threadIdx.x) * 4;
    int m = i >> 9, k = i & 511;
    float4 v = *(const float4*)&src[i];
    *(ushort4*)&dst[((size_t)(k >> 3) * 512 + m) * 8 + (k & 7)] =
        make_ushort4(f2bf(v.x), f2bf(v.y), f2bf(v.z), f2bf(v.w));
}

// ------- M^T partials: Mp[z][j][k] = sum_{e in chunk z} Wq[e,k]*Wk[e,j] -------
__global__ __launch_bounds__(256) void wprep_partial(const float* __restrict__ Wq,
                                                     const float* __restrict__ Wk,
                                                     float* __restrict__ Mp)
{
    __shared__ float As[8][132];
    __shared__ float Bs[8][132];
    const int j0 = blockIdx.x * 128, k0 = blockIdx.y * 128;
    const int e0 = blockIdx.z * 32;
    const int tid = threadIdx.x;
    const int tm = tid & 15, tn = tid >> 4;
    const int le = tid >> 5, lc = (tid & 31) * 4;
    float acc[8][8];
#pragma unroll
    for (int i = 0; i < 8; i++)
#pragma unroll
        for (int j = 0; j < 8; j++) acc[i][j] = 0.f;
    for (int eb = e0; eb < e0 + 32; eb += 8) {
        __syncthreads();
        *(float4*)&As[le][lc] = *(const float4*)&Wq[((size_t)(eb + le)) * 512 + k0 + lc];
        *(float4*)&Bs[le][lc] = *(const float4*)&Wk[((size_t)(eb + le)) * 512 + j0 + lc];
        __syncthreads();
#pragma unroll
        for (int e = 0; e < 8; e++) {
            float a[8], bb[8];
            *(float4*)&a[0] = *(float4*)&As[e][4 * tn];
            *(float4*)&a[4] = *(float4*)&As[e][64 + 4 * tn];
            *(float4*)&bb[0] = *(float4*)&Bs[e][4 * tm];
            *(float4*)&bb[4] = *(float4*)&Bs[e][64 + 4 * tm];
#pragma unroll
            for (int i = 0; i < 8; i++)
#pragma unroll
                for (int j = 0; j < 8; j++)
                    acc[i][j] += a[i] * bb[j];
        }
    }
    float* out = Mp + (size_t)blockIdx.z * 512 * 512;
#pragma unroll
    for (int jj = 0; jj < 8; jj++) {
        int j = j0 + ((jj < 4) ? (4 * tm + jj) : (64 + 4 * tm + jj - 4));
        float4 o0 = make_float4(acc[0][jj], acc[1][jj], acc[2][jj], acc[3][jj]);
        float4 o1 = make_float4(acc[4][jj], acc[5][jj], acc[6][jj], acc[7][jj]);
        *(float4*)&out[(size_t)j * 512 + k0 + 4 * tn] = o0;
        *(float4*)&out[(size_t)j * 512 + k0 + 64 + 4 * tn] = o1;
    }
}

// ------- reduce 16 partials, split to bf16 hi/lo, kc8 layout -------
__global__ __launch_bounds__(256) void reduce_split_m(const float* __restrict__ Mp,
                                                      unsigned short* __restrict__ Mth,
                                                      unsigned short* __restrict__ Mtl)
{
    int i = (blockIdx.x * 256 + threadIdx.x) * 4;
    if (i >= 512 * 512) return;
    float4 s = make_float4(0.f, 0.f, 0.f, 0.f);
#pragma unroll
    for (int z = 0; z < 16; z++) {
        float4 v = *(const float4*)&Mp[(size_t)z * 262144 + i];
        s.x += v.x; s.y += v.y; s.z += v.z; s.w += v.w;
    }
    int j = i >> 9, k = i & 511;
    float f[4] = {s.x, s.y, s.z, s.w};
    unsigned short hh[4], ll[4];
#pragma unroll
    for (int r = 0; r < 4; r++) {
        hh[r] = f2bf(f[r]);
        ll[r] = f2bf(f[r] - bf2f(hh[r]));
    }
    size_t o = ((size_t)(k >> 3) * 512 + j) * 8 + (k & 7);
    *(ushort4*)&Mth[o] = make_ushort4(hh[0], hh[1], hh[2], hh[3]);
    *(ushort4*)&Mtl[o] = make_ushort4(ll[0], ll[1], ll[2], ll[3]);
}

// ---- m97-style MFMA GEMM body: tile 128x128, BK=32, 2-phase dbuf pipeline ----
// A,B in kc8 layout. OMODE: 0 = fp32 natural, 2 = bf16 natural. HASBIAS 0/1.
template<int PASSES, int OMODE, int HASBIAS>
__device__ __forceinline__ void gemm_body(const unsigned short* __restrict__ Ah,
                                          const unsigned short* __restrict__ Al, int nrA,
                                          const unsigned short* __restrict__ Bh,
                                          const unsigned short* __restrict__ Bl,
                                          const float* __restrict__ bias,
                                          void* __restrict__ Cp,
                                          int m0, int n0, short* smem)
{
    const int tid = threadIdx.x;
    const int wid = tid >> 6, lane = tid & 63;
    const int wn = wid >> 1, wm = wid & 1;
    const int lr = lane & 15, lg = lane >> 4;
    constexpr int SEGW = (PASSES == 3) ? 8 : 4;      // glds segments per wave per step
    constexpr int BUFSZ = (PASSES == 3) ? 16384 : 8192; // shorts per buffer

    f32x4 acc[4][4];
#pragma unroll
    for (int i = 0; i < 4; i++)
#pragma unroll
        for (int j = 0; j < 4; j++) acc[i][j] = (f32x4)0.f;

    auto stage = [&](int kc0, short* buf) {
#pragma unroll
        for (int s = 0; s < SEGW; s++) {
            const int sg = wid * SEGW + s;
            const int tile = sg >> 3;                // 0=Ah 1=Bh 2=Al 3=Bl (wave-uniform)
            const int seg = sg & 7;
            const int c = seg >> 1, h = seg & 1;
            const unsigned short* bp;
            size_t ro;
            if (tile == 0)      { bp = Ah; ro = (size_t)(kc0 + c) * (size_t)nrA + n0 + h * 64; }
            else if (tile == 1) { bp = Bh; ro = (size_t)(kc0 + c) * 512 + m0 + h * 64; }
            else if (tile == 2) { bp = Al; ro = (size_t)(kc0 + c) * (size_t)nrA + n0 + h * 64; }
            else                { bp = Bl; ro = (size_t)(kc0 + c) * 512 + m0 + h * 64; }
            glds16(bp + ro * 8 + (size_t)lane * 8, buf + tile * 4096 + seg * 512);
        }
    };

    stage(0, smem);                                  // prologue: fill buffer 0
    for (int step = 0; step < 16; step++) {
        short* cur = smem + (step & 1) * BUFSZ;
        short* nxt = smem + ((step + 1) & 1) * BUFSZ;
        __syncthreads();                             // cur's loads landed; nxt readable-done
        if (step < 15) stage((step + 1) * 4, nxt);   // issue next tile NOW (hides under MFMA)

        bf16x8 a[4], b[4];
#pragma unroll
        for (int f = 0; f < 4; f++) {
            a[f] = *(bf16x8*)&cur[       (lg * 128 + wn * 64 + f * 16 + lr) * 8];
            b[f] = *(bf16x8*)&cur[4096 + (lg * 128 + wm * 64 + f * 16 + lr) * 8];
        }
        if (PASSES == 3) {
            bf16x8 a2[4], b2[4];
#pragma unroll
            for (int f = 0; f < 4; f++) {
                a2[f] = *(bf16x8*)&cur[8192  + (lg * 128 + wn * 64 + f * 16 + lr) * 8];
                b2[f] = *(bf16x8*)&cur[12288 + (lg * 128 + wm * 64 + f * 16 + lr) * 8];
            }
#pragma unroll
            for (int i = 0; i < 4; i++)
#pragma unroll
                for (int j = 0; j < 4; j++) {
                    acc[i][j] = __builtin_amdgcn_mfma_f32_16x16x32_bf16(a[i], b[j], acc[i][j], 0, 0, 0);
                    acc[i][j] = __builtin_amdgcn_mfma_f32_16x16x32_bf16(a[i], b2[j], acc[i][j], 0, 0, 0);
                    acc[i][j] = __builtin_amdgcn_mfma_f32_16x16x32_bf16(a2[i], b[j], acc[i][j], 0, 0, 0);
                }
        } else {
#pragma unroll
            for (int i = 0; i < 4; i++)
#pragma unroll
                for (int j = 0; j < 4; j++)
                    acc[i][j] = __builtin_amdgcn_mfma_f32_16x16x32_bf16(a[i], b[j], acc[i][j], 0, 0, 0);
        }
    }

    float bs[4];
#pragma unroll
    for (int j = 0; j < 4; j++) bs[j] = HASBIAS ? bias[m0 + wm * 64 + j * 16 + lr] : 0.f;

    if (OMODE == 0) {
        float* C = (float*)Cp;
#pragma unroll
        for (int i = 0; i < 4; i++)
#pragma unroll
            for (int j = 0; j < 4; j++) {
                int m = m0 + wm * 64 + j * 16 + lr;
#pragma unroll
                for (int r = 0; r < 4; r++) {
                    int n = n0 + wn * 64 + i * 16 + lg * 4 + r;
                    C[(size_t)n * 512 + m] = acc[i][j][r] + bs[j];
                }
            }
    } else {
        unsigned short* C = (unsigned short*)Cp;
#pragma unroll
        for (int i = 0; i < 4; i++)
#pragma unroll
            for (int j = 0; j < 4; j++) {
                int m = m0 + wm * 64 + j * 16 + lr;
#pragma unroll
                for (int r = 0; r < 4; r++) {
                    int n = n0 + wn * 64 + i * 16 + lg * 4 + r;
                    C[(size_t)n * 512 + m] = f2bf(acc[i][j][r] + bs[j]);
                }
            }
    }
}

// fused dispatch: z=0 -> V GEMM (1-pass, bf16 out), z=1 -> Y GEMM (3-pass, fp32)
__global__ __launch_bounds__(256) void fused_vy(const unsigned short* __restrict__ Ah,
                                                const unsigned short* __restrict__ Wvh,
                                                const float* __restrict__ bv,
                                                unsigned short* __restrict__ Vb,
                                                const unsigned short* __restrict__ Zh,
                                                const unsigned short* __restrict__ Zl,
                                                const unsigned short* __restrict__ Mth,
                                                const unsigned short* __restrict__ Mtl,
                                                float* __restrict__ Y)
{
    __shared__ short smem[32768];                    // 64 KB: 2 x 32KB (3-pass buffers)
    const int m0 = blockIdx.x * 128;
    const int n0 = blockIdx.y * 128;
    if (blockIdx.z == 0) {
        if (blockIdx.y >= 128) return;
        gemm_body<1, 2, 1>(Ah, Ah, NRH, Wvh, Wvh, bv, Vb, m0, n0, smem);
    } else {
        gemm_body<3, 0, 0>(Zh, Zl, ZROWS, Mth, Mtl, nullptr, Y, m0, n0, smem);
    }
}

__global__ __launch_bounds__(256) void o_gemm(const unsigned short* __restrict__ Ag,
                                              const unsigned short* __restrict__ Woh,
                                              const float* __restrict__ bo,
                                              float* __restrict__ C)
{
    __shared__ short smem[16384];                    // 32 KB: 2 x 16KB (1-pass buffers)
    gemm_body<1, 0, 1>(Ag, Ag, NRH, Woh, Woh, bo, C, blockIdx.x * 128, blockIdx.y * 128, smem);
}

// ================= radix-8 register FFT (N = 4096 = 8^4) =================
template<int SGN>
__device__ __forceinline__ void radix8(float* xr, float* xi)
{
    const float C = 0.70710678118654752440f;
    const float S = (float)SGN;
    float t0r = xr[0] + xr[4], t0i = xi[0] + xi[4];
    float t1r = xr[1] + xr[5], t1i = xi[1] + xi[5];
    float t2r = xr[2] + xr[6], t2i = xi[2] + xi[6];
    float t3r = xr[3] + xr[7], t3i = xi[3] + xi[7];
    float u0r = xr[0] - xr[4], u0i = xi[0] - xi[4];
    float a1r = xr[1] - xr[5], a1i = xi[1] - xi[5];
    float a2r = xr[2] - xr[6], a2i = xi[2] - xi[6];
    float a3r = xr[3] - xr[7], a3i = xi[3] - xi[7];
    float u1r = C * (a1r - S * a1i), u1i = C * (S * a1r + a1i);
    float u2r = -S * a2i,             u2i = S * a2r;
    float u3r = -C * (a3r + S * a3i), u3i = C * (S * a3r - a3i);
    float v0r = t0r + t2r, v0i = t0i + t2i;
    float w0r = t0r - t2r, w0i = t0i - t2i;
    float v1r = t1r + t3r, v1i = t1i + t3i;
    float w1r = -S * (t1i - t3i), w1i = S * (t1r - t3r);
    float p0r = u0r + u2r, p0i = u0i + u2i;
    float q0r = u0r - u2r, q0i = u0i - u2i;
    float p1r = u1r + u3r, p1i = u1i + u3i;
    float q1r = -S * (u1i - u3i), q1i = S * (u1r - u3r);
    xr[0] = v0r + v1r; xi[0] = v0i + v1i;
    xr[4] = v0r - v1r; xi[4] = v0i - v1i;
    xr[2] = w0r + w1r; xi[2] = w0i + w1i;
    xr[6] = w0r - w1r; xi[6] = w0i - w1i;
    xr[1] = p0r + p1r; xi[1] = p0i + p1i;
    xr[5] = p0r - p1r; xi[5] = p0i - p1i;
    xr[3] = q0r + q1r; xi[3] = q0i + q1i;
    xr[7] = q0r - q1r; xi[7] = q0i - q1i;
}

__device__ __forceinline__ void twmul(float& xr, float& xi, float wc, float ws)
{
    float a = xr, b = xi;
    xr = a * wc - b * ws;
    xi = a * ws + b * wc;
}

__device__ __forceinline__ void twiddle7(float* xr, float* xi, int n, float ang)
{
    float s1, c1;
    __sincosf(ang * (float)n, &s1, &c1);
    float wc = c1, ws = s1;
    twmul(xr[1], xi[1], wc, ws);
#pragma unroll
    for (int r = 2; r < 8; r++) {
        float nc = wc * c1 - ws * s1;
        float ns = wc * s1 + ws * c1;
        wc = nc; ws = ns;
        twmul(xr[r], xi[r], wc, ws);
    }
}

#define SW(i) ((i) + ((i) >> 3))

template<int SGN>
__device__ __forceinline__ void fft_core(float* xr, float* xi,
                                         float* lre, float* lim, int tid)
{
    const float TW = (float)SGN * 6.28318530717958647693f;
    __syncthreads();
    radix8<SGN>(xr, xi);
    twiddle7(xr, xi, tid, TW / 4096.f);
#pragma unroll
    for (int r = 0; r < 8; r++) {
        int idx = r * 512 + tid;
        lre[SW(idx)] = xr[r]; lim[SW(idx)] = xi[r];
    }
    __syncthreads();
    const int b2 = (tid >> 6) * 512, n2 = tid & 63;
#pragma unroll
    for (int s = 0; s < 8; s++) {
        int idx = b2 + n2 + s * 64;
        xr[s] = lre[SW(idx)]; xi[s] = lim[SW(idx)];
    }
    __syncthreads();
    radix8<SGN>(xr, xi);
    twiddle7(xr, xi, n2, TW / 512.f);
#pragma unroll
    for (int r = 0; r < 8; r++) {
        int idx = b2 + r * 64 + n2;
        lre[SW(idx)] = xr[r]; lim[SW(idx)] = xi[r];
    }
    __syncthreads();
    const int b3 = (tid >> 3) * 64, n3 = tid & 7;
#pragma unroll
    for (int s = 0; s < 8; s++) {
        int idx = b3 + n3 + s * 8;
        xr[s] = lre[SW(idx)]; xi[s] = lim[SW(idx)];
    }
    __syncthreads();
    radix8<SGN>(xr, xi);
    twiddle7(xr, xi, n3, TW / 64.f);
#pragma unroll
    for (int r = 0; r < 8; r++) {
        int idx = b3 + r * 8 + n3;
        lre[SW(idx)] = xr[r]; lim[SW(idx)] = xi[r];
    }
    __syncthreads();
#pragma unroll
    for (int s = 0; s < 8; s++) {
        int idx = tid * 8 + s;
        xr[s] = lre[SW(idx)]; xi[s] = lim[SW(idx)];
    }
    __syncthreads();
    radix8<SGN>(xr, xi);
    const int fr = ((tid & 7) << 6) | (((tid >> 3) & 7) << 3) | (tid >> 6);
#pragma unroll
    for (int r = 0; r < 8; r++) {
        int f = r * 512 + fr;
        lre[SW(f)] = xr[r]; lim[SW(f)] = xi[r];
    }
    __syncthreads();
}

// ------- forward FFT of hidden: 2 packed FFTs (4 channels)/block, kc8 Z out -------
__global__ __launch_bounds__(512) void fft_fwd_z(const float* __restrict__ Htr,
                                                 unsigned short* __restrict__ Zh,
                                                 unsigned short* __restrict__ Zl)
{
    __shared__ float lre[4608];
    __shared__ float lim[4608];
    const int bid = blockIdx.x;          // 0..511
    const int tid = threadIdx.x;
    const int b = bid >> 7;
    const int e0 = (bid & 127) * 4;
    unsigned uh[4][2][2], ul[4][2][2];   // [s][plane][p]
#pragma unroll
    for (int p = 0; p < 2; p++) {
        const float* he = Htr + ((size_t)(b * 512 + e0 + 2 * p)) * 4096;
        const float* ho = Htr + ((size_t)(b * 512 + e0 + 2 * p + 1)) * 4096;
        float xr[8], xi[8];
#pragma unroll
        for (int s = 0; s < 8; s++) {
            xr[s] = he[tid + 512 * s];
            xi[s] = ho[tid + 512 * s];
        }
        fft_core<-1>(xr, xi, lre, lim, tid);
#pragma unroll
        for (int s = 0; s < 4; s++) {
            int f = tid + 512 * s;
            int nf = (4096 - f) & 4095;
            float Ax = lre[SW(f)],  Ay = lim[SW(f)];
            float Bx = lre[SW(nf)], By = lim[SW(nf)];
            float qx = 0.5f * (Ax + Bx), qy = 0.5f * (Ay - By);
            float kx = 0.5f * (Ay + By), ky = -0.5f * (Ax - Bx);
            unsigned short h0 = f2bf(qx), h1 = f2bf(kx);
            uh[s][0][p] = (unsigned)h0 | ((unsigned)h1 << 16);
            ul[s][0][p] = (unsigned)f2bf(qx - bf2f(h0)) | ((unsigned)f2bf(kx - bf2f(h1)) << 16);
            unsigned short h2 = f2bf(qy), h3 = f2bf(ky);
            uh[s][1][p] = (unsigned)h2 | ((unsigned)h3 << 16);
            ul[s][1][p] = (unsigned)f2bf(qy - bf2f(h2)) | ((unsigned)f2bf(ky - bf2f(h3)) << 16);
        }
        if (tid == 0) {
            float vals[2] = {lre[SW(2048)], lim[SW(2048)]};
            size_t row0 = (size_t)(b * 2) * F2 + 2048;
#pragma unroll
            for (int q = 0; q < 2; q++) {
                int e = e0 + 2 * p + q;
                size_t o0 = ((size_t)(e >> 3) * ZROWS + row0) * 8 + (e & 7);
                unsigned short h = f2bf(vals[q]);
                Zh[o0] = h; Zl[o0] = f2bf(vals[q] - bf2f(h));
                size_t o1 = ((size_t)(e >> 3) * ZROWS + row0 + F2) * 8 + (e & 7);
                Zh[o1] = 0; Zl[o1] = 0;
            }
        }
    }
#pragma unroll
    for (int s = 0; s < 4; s++)
#pragma unroll
        for (int c = 0; c < 2; c++) {
            size_t row = (size_t)(b * 2 + c) * F2 + tid + 512 * s;
            size_t off = ((size_t)(e0 >> 3) * ZROWS + row) * 8 + (e0 & 7);
            ushort4 vh = make_ushort4((unsigned short)(uh[s][c][0] & 0xffff),
                                      (unsigned short)(uh[s][c][0] >> 16),
                                      (unsigned short)(uh[s][c][1] & 0xffff),
                                      (unsigned short)(uh[s][c][1] >> 16));
            ushort4 vl = make_ushort4((unsigned short)(ul[s][c][0] & 0xffff),
                                      (unsigned short)(ul[s][c][0] >> 16),
                                      (unsigned short)(ul[s][c][1] & 0xffff),
                                      (unsigned short)(ul[s][c][1] >> 16));
            *(ushort4*)&Zh[off] = vh;
            *(ushort4*)&Zl[off] = vl;
        }
}

// ------- Sp[gz][b][f] = partial sum over 4 e-chunks of Y[row,e] * conj(z[e]) -------
__global__ __launch_bounds__(256) void dot_s(const float* __restrict__ Y,
                                             const unsigned short* __restrict__ Zh,
                                             const unsigned short* __restrict__ Zl,
                                             float2* __restrict__ Sp)
{
    const int f = blockIdx.x * 256 + threadIdx.x;
    const int b = blockIdx.y;
    const int gz = blockIdx.z;
    if (f > 2048) return;
    const size_t row_re = (size_t)(b * 2) * F2 + f;
    const size_t row_im = row_re + F2;
    float sre = 0.f, sim = 0.f;
    for (int c = gz * 4; c < gz * 4 + 4; c++) {
        bf16x8 zrh = *(const bf16x8*)&Zh[((size_t)c * ZROWS + row_re) * 8];
        bf16x8 zrl = *(const bf16x8*)&Zl[((size_t)c * ZROWS + row_re) * 8];
        bf16x8 zih = *(const bf16x8*)&Zh[((size_t)c * ZROWS + row_im) * 8];
        bf16x8 zil = *(const bf16x8*)&Zl[((size_t)c * ZROWS + row_im) * 8];
        float4 yr0 = *(const float4*)&Y[row_re * 512 + c * 8];
        float4 yr1 = *(const float4*)&Y[row_re * 512 + c * 8 + 4];
        float4 yi0 = *(const float4*)&Y[row_im * 512 + c * 8];
        float4 yi1 = *(const float4*)&Y[row_im * 512 + c * 8 + 4];
        float yrv[8] = {yr0.x, yr0.y, yr0.z, yr0.w, yr1.x, yr1.y, yr1.z, yr1.w};
        float yiv[8] = {yi0.x, yi0.y, yi0.z, yi0.w, yi1.x, yi1.y, yi1.z, yi1.w};
#pragma unroll
        for (int j = 0; j < 8; j++) {
            float zr = bf2f((unsigned short)zrh[j]) + bf2f((unsigned short)zrl[j]);
            float zi = bf2f((unsigned short)zih[j]) + bf2f((unsigned short)zil[j]);
            sre += yrv[j] * zr + yiv[j] * zi;
            sim += yiv[j] * zr - yrv[j] * zi;
        }
    }
    Sp[((size_t)gz * 4 + b) * FHP + f] = make_float2(sre, sim);
}

// ---------------- inverse FFT (sums 16 partials) -> ac_mean ----------------
__global__ __launch_bounds__(512) void ifft_kernel(const float2* __restrict__ Sp,
                                                   float* __restrict__ acm)
{
    __shared__ float lre[4608];
    __shared__ float lim[4608];
    const int b = blockIdx.x, tid = threadIdx.x;
    float xr[8], xi[8];
#pragma unroll
    for (int s = 0; s < 8; s++) {
        int idx = tid + 512 * s;
        int src = (idx <= 2048) ? idx : (4096 - idx);
        float sx = 0.f, sy = 0.f;
#pragma unroll
        for (int gz = 0; gz < 16; gz++) {
            float2 v = Sp[((size_t)gz * 4 + b) * FHP + src];
            sx += v.x; sy += v.y;
        }
        xr[s] = sx;
        xi[s] = (idx <= 2048) ? sy : -sy;
    }
    fft_core<1>(xr, xi, lre, lim, tid);
    const float scale = 1.0f / ((float)T_ * (float)E_);
#pragma unroll
    for (int s = 0; s < 8; s++) {
        int p = tid + 512 * s;
        acm[b * T_ + p] = lre[SW(p)] * scale;
    }
}

// ---------------- top-k (24) + softmax, per batch ----------------
__global__ __launch_bounds__(256) void topk_kernel(const float* __restrict__ acm,
                                                   int* __restrict__ delays,
                                                   float* __restrict__ weights)
{
    __shared__ float vals[4096];
    __shared__ float bv[256];
    __shared__ int   bi[256];
    __shared__ float topv[TOPK];
    const int b = blockIdx.x, tid = threadIdx.x;
#pragma unroll
    for (int s = 0; s < 16; s++) vals[tid + 256 * s] = acm[b * T_ + tid + 256 * s];
    __syncthreads();
    for (int it = 0; it < TOPK; it++) {
        float best = -INFINITY; int bidx = 0;
#pragma unroll
        for (int s = 0; s < 16; s++) {
            int idx = tid * 16 + s;
            float v = vals[idx];
            if (v > best) { best = v; bidx = idx; }
        }
        bv[tid] = best; bi[tid] = bidx;
        __syncthreads();
        for (int off = 128; off > 0; off >>= 1) {
            if (tid < off) {
                if (bv[tid + off] > bv[tid] ||
                    (bv[tid + off] == bv[tid] && bi[tid + off] < bi[tid])) {
                    bv[tid] = bv[tid + off]; bi[tid] = bi[tid + off];
                }
            }
            __syncthreads();
        }
        if (tid == 0) {
            delays[b * TOPK + it] = bi[0];
            topv[it] = bv[0];
            vals[bi[0]] = -INFINITY;
        }
        __syncthreads();
    }
    if (tid == 0) {
        float mx = topv[0];
        float w[TOPK], sum = 0.f;
        for (int i = 0; i < TOPK; i++) { w[i] = expf(topv[i] - mx); sum += w[i]; }
        for (int i = 0; i < TOPK; i++) weights[b * TOPK + i] = w[i] / sum;
    }
}

// ---------------- agg: weighted circular gather of bf16 V -> kc8 out ----------------
__global__ __launch_bounds__(256) void agg_kernel(const unsigned short* __restrict__ V,
                                                  const int* __restrict__ delays,
                                                  const float* __restrict__ wts,
                                                  unsigned short* __restrict__ agg)
{
    __shared__ int   dly[B_][TOPK];
    __shared__ float wt[B_][TOPK];
    const int tid = threadIdx.x, b = blockIdx.y;
    if (tid < B_ * TOPK) {
        dly[tid / TOPK][tid % TOPK] = delays[tid];
        wt[tid / TOPK][tid % TOPK]  = wts[tid];
    }
    __syncthreads();
    const int lane = tid & 63, w = tid >> 6;
    const int t = blockIdx.x * 4 + w;
    const int e8 = lane * 8;
    const int h = e8 >> 6;
    const int c = (b * H_ + h) % B_;
    const unsigned short* Vb = V + (size_t)b * T_ * E_;
    float acc[8];
#pragma unroll
    for (int j = 0; j < 8; j++) acc[j] = 0.f;
#pragma unroll
    for (int i = 0; i < TOPK; i++) {
        int tt = (t + dly[c][i]) & (T_ - 1);
        bf16x8 v = *(const bf16x8*)&Vb[(size_t)tt * E_ + e8];
        float wg = wt[c][i];
#pragma unroll
        for (int j = 0; j < 8; j++)
            acc[j] += wg * bf2f((unsigned short)v[j]);
    }
    bf16x8 o;
#pragma unroll
    for (int j = 0; j < 8; j++) o[j] = (short)f2bf(acc[j]);
    int rowg = b * T_ + t;
    *(bf16x8*)&agg[((size_t)(e8 >> 3) * NRH + rowg) * 8] = o;
}

// ---------------- launch ----------------
extern "C" void kernel_launch(void* const* d_in, const int* in_sizes, int n_in,
                              void* d_out, int out_size, void* d_ws, size_t ws_size,
                              hipStream_t stream)
{
    const float* hidden = (const float*)d_in[0];
    const float* Wq = (const float*)d_in[1];
    const float* Wk = (const float*)d_in[3];
    const float* Wv = (const float*)d_in[5]; const float* bv = (const float*)d_in[6];
    const float* Wo = (const float*)d_in[7]; const float* bo = (const float*)d_in[8];

    char* ws = (char*)d_ws;
    const size_t YA_OFF  = 0;                  // 33.8 MB: Htr fp32, later Y fp32
    const size_t AH_OFF  = 33816576;           // 16.8 MB: Ah bf16 kc8, later Ag kc8
    const size_t ZH_OFF  = 50593792;           // 16.9 MB
    const size_t ZL_OFF  = 67502080;           // 16.9 MB
    const size_t VB_OFF  = 84410368;           // 16.8 MB: Mp partials, then Vb bf16 natural
    const size_t MTH_OFF = 101187584;          // 512 KB
    const size_t MTL_OFF = 101711872;          // 512 KB
    const size_t WVH_OFF = 102236160;          // 512 KB
    const size_t WOH_OFF = 102760448;          // 512 KB
    const size_t SP_OFF  = 103284736;          // 1.06 MB (16 partials x 4 x FHP float2)
    const size_t ACM_OFF = 104341504;          // 64 KB
    const size_t DEL_OFF = 104407040;          // 384 B
    const size_t WTS_OFF = 104407424;          // 384 B
    if (ws_size < 104407808) return;

    float* Htr = (float*)(ws + YA_OFF);
    float* Y   = (float*)(ws + YA_OFF);
    unsigned short* Ah  = (unsigned short*)(ws + AH_OFF);
    unsigned short* Ag  = (unsigned short*)(ws + AH_OFF);
    unsigned short* Zh  = (unsigned short*)(ws + ZH_OFF);
    unsigned short* Zl  = (unsigned short*)(ws + ZL_OFF);
    float* Mp           = (float*)(ws + VB_OFF);
    unsigned short* Vb  = (unsigned short*)(ws + VB_OFF);
    unsigned short* Mth = (unsigned short*)(ws + MTH_OFF);
    unsigned short* Mtl = (unsigned short*)(ws + MTL_OFF);
    unsigned short* Wvh = (unsigned short*)(ws + WVH_OFF);
    unsigned short* Woh = (unsigned short*)(ws + WOH_OFF);
    float2* Sp   = (float2*)(ws + SP_OFF);
    float*  acm  = (float*)(ws + ACM_OFF);
    int*    delays = (int*)(ws + DEL_OFF);
    float*  wts    = (float*)(ws + WTS_OFF);

    // prep
    dim3 tg(64, 8, 4);
    trsp_split<<<tg, 256, 0, stream>>>(hidden, Htr, Ah);
    dim3 swg(256, 2);
    split_w2<<<swg, 256, 0, stream>>>(Wv, Wo, Wvh, Woh);
    dim3 mg(4, 4, 16);
    wprep_partial<<<mg, 256, 0, stream>>>(Wq, Wk, Mp);
    reduce_split_m<<<256, 256, 0, stream>>>(Mp, Mth, Mtl);

    // FFT of hidden -> split Z (kc8)
    fft_fwd_z<<<512, 512, 0, stream>>>(Htr, Zh, Zl);

    // fused: V GEMM (z=0) + Y GEMM (z=1), 2-phase pipelined
    dim3 gf(4, 129, 2);
    fused_vy<<<gf, 256, 0, stream>>>(Ah, Wvh, bv, Vb, Zh, Zl, Mth, Mtl, Y);

    // Sp = partial row-dot(Y, conj(Z)), split-K 16
    dim3 dg(9, 4, 16);
    dot_s<<<dg, 256, 0, stream>>>(Y, Zh, Zl, Sp);

    // ac_mean, top-k, gather, output projection
    ifft_kernel<<<B_, 512, 0, stream>>>(Sp, acm);
    topk_kernel<<<B_, 256, 0, stream>>>(acm, delays, wts);
    dim3 ag(T_ / 4, B_);
    agg_kernel<<<ag, 256, 0, stream>>>(Vb, delays, wts, Ag);
    dim3 go(4, 128);
    o_gemm<<<go, 256, 0, stream>>>(Ag, Woh, bo, (float*)d_out);
}